// Round 3
// baseline (2219.883 us; speedup 1.0000x reference)
//
#include <hip/hip_runtime.h>

#define N_NODES   50000
#define N_EDGES   800000
#define N_GRAPHS  256
#define EMB       128
#define L_LAYERS  8
#define N_CLASSES 10
#define BN_EPS    1e-5f
#define NEG_SLOPE 0.01f
#define BM 64
#define NBLK ((N_NODES + BM - 1) / BM)   // 782 mlp blocks

// ---------------------------------------------------------------------------
// CSR build
// ---------------------------------------------------------------------------
__global__ void deg_kernel(const int* __restrict__ ei, int* __restrict__ deg) {
    int e = blockIdx.x * 256 + threadIdx.x;
    if (e < N_EDGES) atomicAdd(&deg[ei[N_EDGES + e]], 1);
}

__global__ void scan_kernel(const int* __restrict__ deg,
                            int* __restrict__ rowptr, int* __restrict__ cursor) {
    __shared__ int sums[256];
    __shared__ int offs[257];
    int t = threadIdx.x;
    const int chunk = (N_NODES + 255) / 256;  // 196
    int start = t * chunk;
    int end   = start + chunk; if (end > N_NODES) end = N_NODES;
    int s = 0;
    for (int i = start; i < end; ++i) s += deg[i];
    sums[t] = s;
    __syncthreads();
    if (t == 0) {
        int a = 0;
        for (int i = 0; i < 256; ++i) { offs[i] = a; a += sums[i]; }
        offs[256] = a;
    }
    __syncthreads();
    int a = offs[t];
    for (int i = start; i < end; ++i) {
        rowptr[i] = a; cursor[i] = a; a += deg[i];
    }
    if (t == 255) rowptr[N_NODES] = offs[256];
}

__global__ void scatter_kernel(const int* __restrict__ ei,
                               int* __restrict__ cursor, int* __restrict__ csr) {
    int e = blockIdx.x * 256 + threadIdx.x;
    if (e < N_EDGES) {
        int d = ei[N_EDGES + e];
        int s = ei[e];
        int p = atomicAdd(&cursor[d], 1);
        csr[p] = s;
    }
}

// Deterministic adjacency: sort each node's neighbor list.
__global__ void sort_adj_kernel(const int* __restrict__ rowptr, int* __restrict__ csr) {
    int node = blockIdx.x * 256 + threadIdx.x;
    if (node >= N_NODES) return;
    int beg = rowptr[node];
    int end = rowptr[node + 1];
    for (int i = beg + 1; i < end; ++i) {
        int v = csr[i];
        int j = i - 1;
        while (j >= beg && csr[j] > v) { csr[j + 1] = csr[j]; --j; }
        csr[j + 1] = v;
    }
}

// ---------------------------------------------------------------------------
// Layer-0 GIN aggregate: hpre[i] = x[i] + sum_{j->i} x[j]  (raw x, csr order)
// ---------------------------------------------------------------------------
__global__ __launch_bounds__(256) void agg_kernel(
        const float* __restrict__ x, const int* __restrict__ rowptr,
        const int* __restrict__ csr, float* __restrict__ hpre) {
    int lane = threadIdx.x & 63;
    int node = __builtin_amdgcn_readfirstlane(blockIdx.x * 4 + (threadIdx.x >> 6));
    if (node >= N_NODES) return;
    int beg = rowptr[node];
    int end = rowptr[node + 1];
    const float2* xp = (const float2*)x;
    float2 acc = xp[(size_t)node * 64 + lane];
    int e = beg;
    for (; e + 3 < end; e += 4) {
        int s0 = csr[e];
        int s1 = csr[e + 1];
        int s2 = csr[e + 2];
        int s3 = csr[e + 3];
        float2 v0 = xp[(size_t)s0 * 64 + lane];
        float2 v1 = xp[(size_t)s1 * 64 + lane];
        float2 v2 = xp[(size_t)s2 * 64 + lane];
        float2 v3 = xp[(size_t)s3 * 64 + lane];
        acc.x += v0.x; acc.y += v0.y;   // keep exact sequential order
        acc.x += v1.x; acc.y += v1.y;
        acc.x += v2.x; acc.y += v2.y;
        acc.x += v3.x; acc.y += v3.y;
    }
    for (; e < end; ++e) {
        int s0 = csr[e];
        float2 v0 = xp[(size_t)s0 * 64 + lane];
        acc.x += v0.x; acc.y += v0.y;
    }
    ((float2*)hpre)[(size_t)node * 64 + lane] = acc;
}

// ---------------------------------------------------------------------------
// Fused finalize(layer l-1) + aggregate(layer l).
// Per node-wave: hb = BN(h_prev); argmax(hb+gumbel) -> nc/gc of layer l-1;
// x = leaky(hb) recomputed per gathered neighbor (identical expressions =>
// identical bits to the old finalize->xnext->agg path; csr add order kept).
// ---------------------------------------------------------------------------
#define XFORM(hin, x0, x1)                                              \
    {                                                                   \
        float t0_ = (hin.x - mu2.x) * iv2.x * g2.x + be2.x;             \
        float t1_ = (hin.y - mu2.y) * iv2.y * g2.y + be2.y;             \
        x0 = (t0_ > 0.f) ? t0_ : NEG_SLOPE * t0_;                       \
        x1 = (t1_ > 0.f) ? t1_ : NEG_SLOPE * t1_;                       \
    }

__global__ __launch_bounds__(256) void gather_fin_kernel(
        const float* __restrict__ hprev,
        const float* __restrict__ mu_v, const float* __restrict__ inv_v,
        const float* __restrict__ gamma, const float* __restrict__ beta,
        const float* __restrict__ gumbel_l, const int* __restrict__ batch,
        const int* __restrict__ rowptr, const int* __restrict__ csr,
        float* __restrict__ nc_out, float* __restrict__ gc_out,
        float* __restrict__ hpre) {
    int lane = threadIdx.x & 63;
    int node = __builtin_amdgcn_readfirstlane(blockIdx.x * 4 + (threadIdx.x >> 6));
    if (node >= N_NODES) return;

    float2 mu2 = ((const float2*)mu_v)[lane];
    float2 iv2 = ((const float2*)inv_v)[lane];
    float2 g2  = ((const float2*)gamma)[lane];
    float2 be2 = ((const float2*)beta)[lane];

    const float2* hp = (const float2*)hprev;
    float2 hv = hp[(size_t)node * 64 + lane];
    float hb0 = (hv.x - mu2.x) * iv2.x * g2.x + be2.x;
    float hb1 = (hv.y - mu2.y) * iv2.y * g2.y + be2.y;

    // ---- finalize part (layer l-1): argmax(hb + gumbel), nc, gc ----
    {
        float2 gm = ((const float2*)gumbel_l)[(size_t)node * 64 + lane];
        float y0 = hb0 + gm.x;   // TAU == 1.0
        float y1 = hb1 + gm.y;
        float bv; int bi;
        if (y1 > y0) { bv = y1; bi = 2 * lane + 1; }
        else         { bv = y0; bi = 2 * lane; }
        #pragma unroll
        for (int off = 32; off > 0; off >>= 1) {
            float ov = __shfl_xor(bv, off);
            int   oi = __shfl_xor(bi, off);
            if (ov > bv || (ov == bv && oi < bi)) { bv = ov; bi = oi; }
        }
        float2 nc;
        nc.x = (bi == 2 * lane)     ? 1.0f : 0.0f;
        nc.y = (bi == 2 * lane + 1) ? 1.0f : 0.0f;
        ((float2*)nc_out)[(size_t)node * 64 + lane] = nc;
        if (lane == 0) atomicExch(&gc_out[(size_t)batch[node] * EMB + bi], 1.0f);
    }

    // ---- aggregate part (layer l): acc = x[node] + sum x[nbr], csr order ----
    float2 acc;
    acc.x = (hb0 > 0.f) ? hb0 : NEG_SLOPE * hb0;
    acc.y = (hb1 > 0.f) ? hb1 : NEG_SLOPE * hb1;

    int beg = rowptr[node];
    int end = rowptr[node + 1];
    int e = beg;
    for (; e + 3 < end; e += 4) {
        int s0 = csr[e];
        int s1 = csr[e + 1];
        int s2 = csr[e + 2];
        int s3 = csr[e + 3];
        float2 h0 = hp[(size_t)s0 * 64 + lane];
        float2 h1 = hp[(size_t)s1 * 64 + lane];
        float2 h2 = hp[(size_t)s2 * 64 + lane];
        float2 h3 = hp[(size_t)s3 * 64 + lane];
        float a0, b0v, a1, b1v, a2, b2v, a3, b3v;
        XFORM(h0, a0, b0v)
        XFORM(h1, a1, b1v)
        XFORM(h2, a2, b2v)
        XFORM(h3, a3, b3v)
        acc.x += a0; acc.y += b0v;   // keep exact sequential order
        acc.x += a1; acc.y += b1v;
        acc.x += a2; acc.y += b2v;
        acc.x += a3; acc.y += b3v;
    }
    for (; e < end; ++e) {
        int s0 = csr[e];
        float2 h0 = hp[(size_t)s0 * 64 + lane];
        float a0, b0v;
        XFORM(h0, a0, b0v)
        acc.x += a0; acc.y += b0v;
    }
    ((float2*)hpre)[(size_t)node * 64 + lane] = acc;
}

// ---------------------------------------------------------------------------
// Fused MLP (Round-1 structure, known-good): H = leaky(HB @ W1 + b1) @ W2 + b2
// in place + per-block BN partials; cols per thread {4tx+j, 64+4tx+j} so the
// Ws b128 reads are stride-4tx (2-way = free).  Appended: fence+counter tail,
// last block reduces pstat -> mu/inv (same b=0..781 order as bn_stats did).
// ---------------------------------------------------------------------------
__global__ __launch_bounds__(256) void mlp_kernel(
        float* __restrict__ HB,
        const float* __restrict__ W1, const float* __restrict__ b1,
        const float* __restrict__ W2, const float* __restrict__ b2,
        float* __restrict__ pstat,
        float* __restrict__ mu_v, float* __restrict__ inv_v,
        int* __restrict__ ctr) {
    __shared__ float As[BM][EMB + 4];
    __shared__ float Ws[32][EMB];
    __shared__ int isLast;

    int t   = threadIdx.x;
    int tx  = t & 15;
    int ty  = t >> 4;
    int row0 = blockIdx.x * BM;

    {
        const float4* Ag = (const float4*)HB;
        #pragma unroll
        for (int rep = 0; rep < 8; ++rep) {
            int v  = t + rep * 256;
            int r  = v >> 5;
            int c4 = v & 31;
            int gr = row0 + r;
            float4 val = (gr < N_NODES) ? Ag[(size_t)gr * 32 + c4]
                                        : make_float4(0.f, 0.f, 0.f, 0.f);
            *(float4*)&As[r][c4 * 4] = val;
        }
    }

    float acc[4][8];
    #pragma unroll
    for (int i = 0; i < 4; ++i)
        #pragma unroll
        for (int j = 0; j < 8; ++j) acc[i][j] = 0.f;

    // phase 1: T = leaky(A @ W1 + b1)
    for (int kk = 0; kk < EMB; kk += 32) {
        __syncthreads();
        const float4* Wg = (const float4*)(W1 + kk * EMB);
        #pragma unroll
        for (int rep = 0; rep < 4; ++rep) {
            int v = t + rep * 256;
            *(float4*)&Ws[v >> 5][(v & 31) * 4] = Wg[v];
        }
        __syncthreads();
        #pragma unroll 4
        for (int k2 = 0; k2 < 32; ++k2) {
            float a[4], b[8];
            #pragma unroll
            for (int i = 0; i < 4; ++i) a[i] = As[ty * 4 + i][kk + k2];
            float4 bb0 = *(float4*)&Ws[k2][tx * 4];
            float4 bb1 = *(float4*)&Ws[k2][64 + tx * 4];
            b[0]=bb0.x; b[1]=bb0.y; b[2]=bb0.z; b[3]=bb0.w;
            b[4]=bb1.x; b[5]=bb1.y; b[6]=bb1.z; b[7]=bb1.w;
            #pragma unroll
            for (int i = 0; i < 4; ++i)
                #pragma unroll
                for (int j = 0; j < 8; ++j) acc[i][j] += a[i] * b[j];
        }
    }

    __syncthreads();
    #pragma unroll
    for (int j = 0; j < 8; ++j) {
        int c = (j < 4) ? (tx * 4 + j) : (64 + tx * 4 + (j - 4));
        float bias = b1[c];
        #pragma unroll
        for (int i = 0; i < 4; ++i) {
            float v = acc[i][j] + bias;
            As[ty * 4 + i][c] = (v > 0.f) ? v : NEG_SLOPE * v;
            acc[i][j] = 0.f;
        }
    }

    // phase 2: H = T @ W2 + b2
    for (int kk = 0; kk < EMB; kk += 32) {
        __syncthreads();
        const float4* Wg = (const float4*)(W2 + kk * EMB);
        #pragma unroll
        for (int rep = 0; rep < 4; ++rep) {
            int v = t + rep * 256;
            *(float4*)&Ws[v >> 5][(v & 31) * 4] = Wg[v];
        }
        __syncthreads();
        #pragma unroll 4
        for (int k2 = 0; k2 < 32; ++k2) {
            float a[4], b[8];
            #pragma unroll
            for (int i = 0; i < 4; ++i) a[i] = As[ty * 4 + i][kk + k2];
            float4 bb0 = *(float4*)&Ws[k2][tx * 4];
            float4 bb1 = *(float4*)&Ws[k2][64 + tx * 4];
            b[0]=bb0.x; b[1]=bb0.y; b[2]=bb0.z; b[3]=bb0.w;
            b[4]=bb1.x; b[5]=bb1.y; b[6]=bb1.z; b[7]=bb1.w;
            #pragma unroll
            for (int i = 0; i < 4; ++i)
                #pragma unroll
                for (int j = 0; j < 8; ++j) acc[i][j] += a[i] * b[j];
        }
    }

    // epilogue: bias, store H, per-column block-partial stats
    float csum[8], csq[8];
    #pragma unroll
    for (int j = 0; j < 8; ++j) { csum[j] = 0.f; csq[j] = 0.f; }

    #pragma unroll
    for (int i = 0; i < 4; ++i) {
        int gr = row0 + ty * 4 + i;
        if (gr < N_NODES) {
            float tmp[8];
            #pragma unroll
            for (int j = 0; j < 8; ++j) {
                int c = (j < 4) ? (tx * 4 + j) : (64 + tx * 4 + (j - 4));
                float v = acc[i][j] + b2[c];
                tmp[j] = v;
                csum[j] += v;
                csq[j]  += v * v;
            }
            float4 o0, o1;
            o0.x=tmp[0]; o0.y=tmp[1]; o0.z=tmp[2]; o0.w=tmp[3];
            o1.x=tmp[4]; o1.y=tmp[5]; o1.z=tmp[6]; o1.w=tmp[7];
            *(float4*)&HB[(size_t)gr * EMB + tx * 4]      = o0;
            *(float4*)&HB[(size_t)gr * EMB + 64 + tx * 4] = o1;
        }
    }

    // reduce stats across ty in LDS, write interleaved per-block partials
    float* red = &Ws[0][0];
    __syncthreads();
    #pragma unroll
    for (int j = 0; j < 8; ++j) {
        int c = (j < 4) ? (tx * 4 + j) : (64 + tx * 4 + (j - 4));
        red[ty * EMB + c] = csum[j];
    }
    __syncthreads();
    float s1 = 0.f;
    if (t < EMB) {
        #pragma unroll
        for (int r = 0; r < 16; ++r) s1 += red[r * EMB + t];
    }
    __syncthreads();
    #pragma unroll
    for (int j = 0; j < 8; ++j) {
        int c = (j < 4) ? (tx * 4 + j) : (64 + tx * 4 + (j - 4));
        red[ty * EMB + c] = csq[j];
    }
    __syncthreads();
    if (t < EMB) {
        float s2 = 0.f;
        #pragma unroll
        for (int r = 0; r < 16; ++r) s2 += red[r * EMB + t];
        float2 o; o.x = s1; o.y = s2;
        *(float2*)&pstat[(size_t)blockIdx.x * 256 + 2 * t] = o;
    }

    // --- BN tail: last finishing block reduces pstat -> mu/inv ---
    __threadfence();               // release this block's pstat writes
    __syncthreads();
    if (t == 0) isLast = (atomicAdd(ctr, 1) == NBLK - 1);
    __syncthreads();
    if (isLast) {
        __threadfence();           // acquire all blocks' pstat writes
        if (t < EMB) {
            float s = 0.f, q = 0.f;
            const float2* p = (const float2*)pstat;  // [b][128] float2
            int b = 0;
            for (; b + 4 <= NBLK; b += 4) {
                float2 v0 = p[(size_t)(b + 0) * 128 + t];
                float2 v1 = p[(size_t)(b + 1) * 128 + t];
                float2 v2 = p[(size_t)(b + 2) * 128 + t];
                float2 v3 = p[(size_t)(b + 3) * 128 + t];
                s += v0.x; q += v0.y;
                s += v1.x; q += v1.y;
                s += v2.x; q += v2.y;
                s += v3.x; q += v3.y;
            }
            for (; b < NBLK; ++b) {
                float2 v = p[(size_t)b * 128 + t];
                s += v.x; q += v.y;
            }
            const float invN = 1.f / (float)N_NODES;
            float mu  = s * invN;
            float var = q * invN - mu * mu;
            mu_v[t]  = mu;
            inv_v[t] = rsqrtf(var + BN_EPS);
        }
    }
}

// ---------------------------------------------------------------------------
// Tail finalize for the last layer (no aggregation, no xnext)
// ---------------------------------------------------------------------------
__global__ __launch_bounds__(256) void finalize_tail_kernel(
        const float* __restrict__ h,
        const float* __restrict__ mu_v, const float* __restrict__ inv_v,
        const float* __restrict__ gamma, const float* __restrict__ beta,
        const float* __restrict__ gumbel_l, const int* __restrict__ batch,
        float* __restrict__ nc_out, float* __restrict__ gc_out) {
    int lane = threadIdx.x & 63;
    int node = blockIdx.x * 4 + (threadIdx.x >> 6);

    float2 hv  = ((const float2*)h)[(size_t)node * 64 + lane];
    float2 mu2 = ((const float2*)mu_v)[lane];
    float2 iv2 = ((const float2*)inv_v)[lane];
    float2 g2  = ((const float2*)gamma)[lane];
    float2 be2 = ((const float2*)beta)[lane];
    float2 gm  = ((const float2*)gumbel_l)[(size_t)node * 64 + lane];

    float hb0 = (hv.x - mu2.x) * iv2.x * g2.x + be2.x;
    float hb1 = (hv.y - mu2.y) * iv2.y * g2.y + be2.y;
    float y0 = hb0 + gm.x;   // TAU == 1.0
    float y1 = hb1 + gm.y;

    float bv; int bi;
    if (y1 > y0) { bv = y1; bi = 2 * lane + 1; }
    else         { bv = y0; bi = 2 * lane; }
    #pragma unroll
    for (int off = 32; off > 0; off >>= 1) {
        float ov = __shfl_xor(bv, off);
        int   oi = __shfl_xor(bi, off);
        if (ov > bv || (ov == bv && oi < bi)) { bv = ov; bi = oi; }
    }

    float2 nc;
    nc.x = (bi == 2 * lane)     ? 1.0f : 0.0f;
    nc.y = (bi == 2 * lane + 1) ? 1.0f : 0.0f;
    ((float2*)nc_out)[(size_t)node * 64 + lane] = nc;

    if (lane == 0) atomicExch(&gc_out[(size_t)batch[node] * EMB + bi], 1.0f);
}

// ---------------------------------------------------------------------------
// logits = gc_last @ dense_W + dense_b
// ---------------------------------------------------------------------------
__global__ __launch_bounds__(128) void logits_kernel(
        const float* __restrict__ gc, const float* __restrict__ W,
        const float* __restrict__ b, float* __restrict__ out) {
    __shared__ float row[EMB];
    int g = blockIdx.x;
    int t = threadIdx.x;
    row[t] = gc[g * EMB + t];
    __syncthreads();
    if (t < N_CLASSES) {
        float acc = b[t];
        for (int k = 0; k < EMB; ++k) acc += row[k] * W[k * N_CLASSES + t];
        out[g * N_CLASSES + t] = acc;
    }
}

// ---------------------------------------------------------------------------
extern "C" void kernel_launch(void* const* d_in, const int* in_sizes, int n_in,
                              void* d_out, int out_size, void* d_ws, size_t ws_size,
                              hipStream_t stream) {
    const float* x_in    = (const float*)d_in[0];
    const int*   ei      = (const int*)  d_in[1];
    const int*   batch   = (const int*)  d_in[2];
    const float* W1      = (const float*)d_in[3];
    const float* b1      = (const float*)d_in[4];
    const float* W2      = (const float*)d_in[5];
    const float* b2      = (const float*)d_in[6];
    const float* gamma   = (const float*)d_in[7];
    const float* beta    = (const float*)d_in[8];
    const float* gumbel  = (const float*)d_in[9];
    const float* dW      = (const float*)d_in[10];
    const float* db      = (const float*)d_in[11];

    float* out = (float*)d_out;
    const size_t NC_OFF = (size_t)N_GRAPHS * N_CLASSES;
    const size_t GC_OFF = NC_OFF + (size_t)L_LAYERS * N_NODES * EMB;
    float* logits_out = out;
    float* nc_out     = out + NC_OFF;
    float* gc_out     = out + GC_OFF;

    // workspace layout
    float* bufA    = (float*)d_ws;                    // 6.4M floats
    float* bufB    = bufA + (size_t)N_NODES * EMB;    // 6.4M floats
    float* pstat   = bufB + (size_t)N_NODES * EMB;    // NBLK*256 (sum/sq interleaved)
    float* mu_v    = pstat + (size_t)NBLK * 256;      // 128
    float* inv_v   = mu_v + EMB;                      // 128
    int*   rowptr  = (int*)(inv_v + EMB);             // 50001
    int*   cursor  = rowptr + (N_NODES + 1);          // 50000
    int*   csr     = cursor + N_NODES;                // 800000
    int*   deg     = csr + N_EDGES;                   // 50000
    int*   ctr     = deg + N_NODES;                   // 8 (per-layer counters)

    // CSR build (deterministic after per-node sort); memset also zeroes ctr
    hipMemsetAsync(deg, 0, (N_NODES + L_LAYERS) * sizeof(int), stream);
    deg_kernel<<<(N_EDGES + 255) / 256, 256, 0, stream>>>(ei, deg);
    scan_kernel<<<1, 256, 0, stream>>>(deg, rowptr, cursor);
    scatter_kernel<<<(N_EDGES + 255) / 256, 256, 0, stream>>>(ei, cursor, csr);
    sort_adj_kernel<<<(N_NODES + 255) / 256, 256, 0, stream>>>(rowptr, csr);

    hipMemsetAsync(gc_out, 0,
                   (size_t)L_LAYERS * N_GRAPHS * EMB * sizeof(float), stream);

    float* buf[2] = { bufA, bufB };

    // layer 0: raw aggregate from x_in
    agg_kernel<<<(N_NODES + 3) / 4, 256, 0, stream>>>(x_in, rowptr, csr, bufA);
    mlp_kernel<<<NBLK, 256, 0, stream>>>(
        bufA, W1, b1, W2, b2, pstat, mu_v, inv_v, ctr + 0);

    for (int l = 1; l < L_LAYERS; ++l) {
        float* hprev = buf[(l - 1) & 1];
        float* hcur  = buf[l & 1];
        gather_fin_kernel<<<(N_NODES + 3) / 4, 256, 0, stream>>>(
            hprev, mu_v, inv_v,
            gamma + (size_t)(l - 1) * EMB, beta + (size_t)(l - 1) * EMB,
            gumbel + (size_t)(l - 1) * N_NODES * EMB, batch,
            rowptr, csr,
            nc_out + (size_t)(l - 1) * N_NODES * EMB,
            gc_out + (size_t)(l - 1) * N_GRAPHS * EMB,
            hcur);
        mlp_kernel<<<NBLK, 256, 0, stream>>>(
            hcur,
            W1 + (size_t)l * EMB * EMB, b1 + (size_t)l * EMB,
            W2 + (size_t)l * EMB * EMB, b2 + (size_t)l * EMB,
            pstat, mu_v, inv_v, ctr + l);
    }

    // finalize last layer (no aggregation)
    finalize_tail_kernel<<<(N_NODES + 3) / 4, 256, 0, stream>>>(
        buf[(L_LAYERS - 1) & 1], mu_v, inv_v,
        gamma + (size_t)(L_LAYERS - 1) * EMB, beta + (size_t)(L_LAYERS - 1) * EMB,
        gumbel + (size_t)(L_LAYERS - 1) * N_NODES * EMB, batch,
        nc_out + (size_t)(L_LAYERS - 1) * N_NODES * EMB,
        gc_out + (size_t)(L_LAYERS - 1) * N_GRAPHS * EMB);

    logits_kernel<<<N_GRAPHS, 128, 0, stream>>>(
        gc_out + (size_t)(L_LAYERS - 1) * N_GRAPHS * EMB, dW, db, logits_out);
}

// Round 4
// 1847.119 us; speedup vs baseline: 1.2018x; 1.2018x over previous
//
#include <hip/hip_runtime.h>

#define N_NODES   50000
#define N_EDGES   800000
#define N_GRAPHS  256
#define EMB       128
#define L_LAYERS  8
#define N_CLASSES 10
#define BN_EPS    1e-5f
#define NEG_SLOPE 0.01f
#define BM 64
#define NBLK ((N_NODES + BM - 1) / BM)   // 782 mlp blocks

// ---------------------------------------------------------------------------
// CSR build
// ---------------------------------------------------------------------------
__global__ void deg_kernel(const int* __restrict__ ei, int* __restrict__ deg) {
    int e = blockIdx.x * 256 + threadIdx.x;
    if (e < N_EDGES) atomicAdd(&deg[ei[N_EDGES + e]], 1);
}

__global__ void scan_kernel(const int* __restrict__ deg,
                            int* __restrict__ rowptr, int* __restrict__ cursor) {
    __shared__ int sums[256];
    __shared__ int offs[257];
    int t = threadIdx.x;
    const int chunk = (N_NODES + 255) / 256;  // 196
    int start = t * chunk;
    int end   = start + chunk; if (end > N_NODES) end = N_NODES;
    int s = 0;
    for (int i = start; i < end; ++i) s += deg[i];
    sums[t] = s;
    __syncthreads();
    if (t == 0) {
        int a = 0;
        for (int i = 0; i < 256; ++i) { offs[i] = a; a += sums[i]; }
        offs[256] = a;
    }
    __syncthreads();
    int a = offs[t];
    for (int i = start; i < end; ++i) {
        rowptr[i] = a; cursor[i] = a; a += deg[i];
    }
    if (t == 255) rowptr[N_NODES] = offs[256];
}

__global__ void scatter_kernel(const int* __restrict__ ei,
                               int* __restrict__ cursor, int* __restrict__ csr) {
    int e = blockIdx.x * 256 + threadIdx.x;
    if (e < N_EDGES) {
        int d = ei[N_EDGES + e];
        int s = ei[e];
        int p = atomicAdd(&cursor[d], 1);
        csr[p] = s;
    }
}

// Deterministic adjacency: sort each node's neighbor list.
__global__ void sort_adj_kernel(const int* __restrict__ rowptr, int* __restrict__ csr) {
    int node = blockIdx.x * 256 + threadIdx.x;
    if (node >= N_NODES) return;
    int beg = rowptr[node];
    int end = rowptr[node + 1];
    for (int i = beg + 1; i < end; ++i) {
        int v = csr[i];
        int j = i - 1;
        while (j >= beg && csr[j] > v) { csr[j + 1] = csr[j]; --j; }
        csr[j + 1] = v;
    }
}

// ---------------------------------------------------------------------------
// Layer-0 GIN aggregate: hpre[i] = x[i] + sum_{j->i} x[j]  (raw x, csr order)
// ---------------------------------------------------------------------------
__global__ __launch_bounds__(256) void agg_kernel(
        const float* __restrict__ x, const int* __restrict__ rowptr,
        const int* __restrict__ csr, float* __restrict__ hpre) {
    int lane = threadIdx.x & 63;
    int node = __builtin_amdgcn_readfirstlane(blockIdx.x * 4 + (threadIdx.x >> 6));
    if (node >= N_NODES) return;
    int beg = rowptr[node];
    int end = rowptr[node + 1];
    const float2* xp = (const float2*)x;
    float2 acc = xp[(size_t)node * 64 + lane];
    int e = beg;
    for (; e + 3 < end; e += 4) {
        int s0 = csr[e];
        int s1 = csr[e + 1];
        int s2 = csr[e + 2];
        int s3 = csr[e + 3];
        float2 v0 = xp[(size_t)s0 * 64 + lane];
        float2 v1 = xp[(size_t)s1 * 64 + lane];
        float2 v2 = xp[(size_t)s2 * 64 + lane];
        float2 v3 = xp[(size_t)s3 * 64 + lane];
        acc.x += v0.x; acc.y += v0.y;   // keep exact sequential order
        acc.x += v1.x; acc.y += v1.y;
        acc.x += v2.x; acc.y += v2.y;
        acc.x += v3.x; acc.y += v3.y;
    }
    for (; e < end; ++e) {
        int s0 = csr[e];
        float2 v0 = xp[(size_t)s0 * 64 + lane];
        acc.x += v0.x; acc.y += v0.y;
    }
    ((float2*)hpre)[(size_t)node * 64 + lane] = acc;
}

// ---------------------------------------------------------------------------
// Fused finalize(layer l-1) + aggregate(layer l).
// ---------------------------------------------------------------------------
#define XFORM(hin, x0, x1)                                              \
    {                                                                   \
        float t0_ = (hin.x - mu2.x) * iv2.x * g2.x + be2.x;             \
        float t1_ = (hin.y - mu2.y) * iv2.y * g2.y + be2.y;             \
        x0 = (t0_ > 0.f) ? t0_ : NEG_SLOPE * t0_;                       \
        x1 = (t1_ > 0.f) ? t1_ : NEG_SLOPE * t1_;                       \
    }

__global__ __launch_bounds__(256) void gather_fin_kernel(
        const float* __restrict__ hprev,
        const float* __restrict__ mu_v, const float* __restrict__ inv_v,
        const float* __restrict__ gamma, const float* __restrict__ beta,
        const float* __restrict__ gumbel_l, const int* __restrict__ batch,
        const int* __restrict__ rowptr, const int* __restrict__ csr,
        float* __restrict__ nc_out, float* __restrict__ gc_out,
        float* __restrict__ hpre) {
    int lane = threadIdx.x & 63;
    int node = __builtin_amdgcn_readfirstlane(blockIdx.x * 4 + (threadIdx.x >> 6));
    if (node >= N_NODES) return;

    float2 mu2 = ((const float2*)mu_v)[lane];
    float2 iv2 = ((const float2*)inv_v)[lane];
    float2 g2  = ((const float2*)gamma)[lane];
    float2 be2 = ((const float2*)beta)[lane];

    const float2* hp = (const float2*)hprev;
    float2 hv = hp[(size_t)node * 64 + lane];
    float hb0 = (hv.x - mu2.x) * iv2.x * g2.x + be2.x;
    float hb1 = (hv.y - mu2.y) * iv2.y * g2.y + be2.y;

    // ---- finalize part (layer l-1): argmax(hb + gumbel), nc, gc ----
    {
        float2 gm = ((const float2*)gumbel_l)[(size_t)node * 64 + lane];
        float y0 = hb0 + gm.x;   // TAU == 1.0
        float y1 = hb1 + gm.y;
        float bv; int bi;
        if (y1 > y0) { bv = y1; bi = 2 * lane + 1; }
        else         { bv = y0; bi = 2 * lane; }
        #pragma unroll
        for (int off = 32; off > 0; off >>= 1) {
            float ov = __shfl_xor(bv, off);
            int   oi = __shfl_xor(bi, off);
            if (ov > bv || (ov == bv && oi < bi)) { bv = ov; bi = oi; }
        }
        float2 nc;
        nc.x = (bi == 2 * lane)     ? 1.0f : 0.0f;
        nc.y = (bi == 2 * lane + 1) ? 1.0f : 0.0f;
        ((float2*)nc_out)[(size_t)node * 64 + lane] = nc;
        if (lane == 0) atomicExch(&gc_out[(size_t)batch[node] * EMB + bi], 1.0f);
    }

    // ---- aggregate part (layer l): acc = x[node] + sum x[nbr], csr order ----
    float2 acc;
    acc.x = (hb0 > 0.f) ? hb0 : NEG_SLOPE * hb0;
    acc.y = (hb1 > 0.f) ? hb1 : NEG_SLOPE * hb1;

    int beg = rowptr[node];
    int end = rowptr[node + 1];
    int e = beg;
    for (; e + 3 < end; e += 4) {
        int s0 = csr[e];
        int s1 = csr[e + 1];
        int s2 = csr[e + 2];
        int s3 = csr[e + 3];
        float2 h0 = hp[(size_t)s0 * 64 + lane];
        float2 h1 = hp[(size_t)s1 * 64 + lane];
        float2 h2 = hp[(size_t)s2 * 64 + lane];
        float2 h3 = hp[(size_t)s3 * 64 + lane];
        float a0, b0v, a1, b1v, a2, b2v, a3, b3v;
        XFORM(h0, a0, b0v)
        XFORM(h1, a1, b1v)
        XFORM(h2, a2, b2v)
        XFORM(h3, a3, b3v)
        acc.x += a0; acc.y += b0v;   // keep exact sequential order
        acc.x += a1; acc.y += b1v;
        acc.x += a2; acc.y += b2v;
        acc.x += a3; acc.y += b3v;
    }
    for (; e < end; ++e) {
        int s0 = csr[e];
        float2 h0 = hp[(size_t)s0 * 64 + lane];
        float a0, b0v;
        XFORM(h0, a0, b0v)
        acc.x += a0; acc.y += b0v;
    }
    ((float2*)hpre)[(size_t)node * 64 + lane] = acc;
}

// ---------------------------------------------------------------------------
// Fused MLP, wave-column structure:
//   lane  = row   (0..63 of the 64-row tile)
//   wave  = column strip (wid*32 .. wid*32+31)
// W/b accesses have NO lane dependence -> scalar s_load, SGPR operand to FMA.
// Only LDS traffic in the K loop: one ds_read_b128 of A per 4 k-steps.
// Accumulation per output is strict k=0..127 ascending (bitwise-identical);
// BN partials are strict ascending-row sums over valid rows (as before).
// ---------------------------------------------------------------------------
__global__ __launch_bounds__(256) void mlp_kernel(
        float* __restrict__ HB,
        const float* __restrict__ W1, const float* __restrict__ b1,
        const float* __restrict__ W2, const float* __restrict__ b2,
        float* __restrict__ pstat) {
    __shared__ float As[BM][EMB + 4];   // 64 x 132 = 33.8 KB

    const int t    = threadIdx.x;
    const int lane = t & 63;
    const int wid  = __builtin_amdgcn_readfirstlane(t >> 6);
    const int wcol = wid * 32;
    const int row0 = blockIdx.x * BM;

    // ---- stage A tile (row-major, zero-padded tail rows) ----
    {
        const float4* Ag = (const float4*)HB;
        #pragma unroll
        for (int rep = 0; rep < 8; ++rep) {
            int v  = t + rep * 256;
            int r  = v >> 5;
            int c4 = v & 31;
            int gr = row0 + r;
            float4 val = (gr < N_NODES) ? Ag[(size_t)gr * 32 + c4]
                                        : make_float4(0.f, 0.f, 0.f, 0.f);
            *(float4*)&As[r][c4 * 4] = val;
        }
    }
    __syncthreads();

    float acc[32];
    #pragma unroll
    for (int j = 0; j < 32; ++j) acc[j] = 0.f;

    // ---- phase 1: acc = A(row) @ W1(:, wcol..wcol+31), k ascending ----
    {
        const float* Wb = W1 + wcol;
        #pragma unroll 2
        for (int k4 = 0; k4 < 32; ++k4) {
            float4 a4 = *(const float4*)&As[lane][k4 * 4];
            const float* wk = Wb + (size_t)(k4 * 4) * EMB;
            #pragma unroll
            for (int dk = 0; dk < 4; ++dk) {
                float a = (dk == 0) ? a4.x : (dk == 1) ? a4.y
                         : (dk == 2) ? a4.z : a4.w;
                const float* w = wk + (size_t)dk * EMB;
                #pragma unroll
                for (int j = 0; j < 32; ++j) acc[j] += a * w[j];
            }
        }
    }

    __syncthreads();   // all phase-1 reads of As done before T overwrites it

    // ---- transform: T = leaky(acc + b1), write back to As[lane][wcol+j] ----
    {
        float tv[32];
        #pragma unroll
        for (int j = 0; j < 32; ++j) {
            float v = acc[j] + b1[wcol + j];
            tv[j] = (v > 0.f) ? v : NEG_SLOPE * v;
            acc[j] = 0.f;
        }
        #pragma unroll
        for (int q = 0; q < 8; ++q)
            *(float4*)&As[lane][wcol + q * 4] =
                make_float4(tv[q * 4 + 0], tv[q * 4 + 1],
                            tv[q * 4 + 2], tv[q * 4 + 3]);
    }
    __syncthreads();   // T visible to all waves

    // ---- phase 2: acc = T(row) @ W2(:, wcol..wcol+31), k ascending ----
    {
        const float* Wb = W2 + wcol;
        #pragma unroll 2
        for (int k4 = 0; k4 < 32; ++k4) {
            float4 a4 = *(const float4*)&As[lane][k4 * 4];
            const float* wk = Wb + (size_t)(k4 * 4) * EMB;
            #pragma unroll
            for (int dk = 0; dk < 4; ++dk) {
                float a = (dk == 0) ? a4.x : (dk == 1) ? a4.y
                         : (dk == 2) ? a4.z : a4.w;
                const float* w = wk + (size_t)dk * EMB;
                #pragma unroll
                for (int j = 0; j < 32; ++j) acc[j] += a * w[j];
            }
        }
    }

    // ---- epilogue: h = acc + b2; store to global; stash in LDS for stats ----
    float hv[32];
    #pragma unroll
    for (int j = 0; j < 32; ++j) hv[j] = acc[j] + b2[wcol + j];

    const int gr = row0 + lane;
    if (gr < N_NODES) {
        #pragma unroll
        for (int q = 0; q < 8; ++q)
            *(float4*)&HB[(size_t)gr * EMB + wcol + q * 4] =
                make_float4(hv[q * 4 + 0], hv[q * 4 + 1],
                            hv[q * 4 + 2], hv[q * 4 + 3]);
    }

    __syncthreads();   // all phase-2 reads of As done before h overwrites it
    #pragma unroll
    for (int q = 0; q < 8; ++q)
        *(float4*)&As[lane][wcol + q * 4] =
            make_float4(hv[q * 4 + 0], hv[q * 4 + 1],
                        hv[q * 4 + 2], hv[q * 4 + 3]);
    __syncthreads();

    // ---- per-block BN partials: strict ascending-row sum over valid rows ----
    if (t < EMB) {
        int valid = N_NODES - row0; if (valid > BM) valid = BM;
        float s = 0.f, q = 0.f;
        for (int r = 0; r < valid; ++r) {
            float v = As[r][t];
            s += v;
            q += v * v;
        }
        float2 o; o.x = s; o.y = q;
        *(float2*)&pstat[(size_t)blockIdx.x * 256 + 2 * t] = o;
    }
}

// Fixed-order reduction of per-block partials -> mu / inv (b = 0..781)
__global__ __launch_bounds__(128) void bn_stats_kernel(
        const float* __restrict__ pstat,
        float* __restrict__ mu_out, float* __restrict__ inv_out) {
    int t = threadIdx.x;
    float s = 0.f, q = 0.f;
    const float2* p = (const float2*)pstat;  // [b][128] float2
    int b = 0;
    for (; b + 4 <= NBLK; b += 4) {
        float2 v0 = p[(size_t)(b + 0) * 128 + t];
        float2 v1 = p[(size_t)(b + 1) * 128 + t];
        float2 v2 = p[(size_t)(b + 2) * 128 + t];
        float2 v3 = p[(size_t)(b + 3) * 128 + t];
        s += v0.x; q += v0.y;
        s += v1.x; q += v1.y;
        s += v2.x; q += v2.y;
        s += v3.x; q += v3.y;
    }
    for (; b < NBLK; ++b) {
        float2 v = p[(size_t)b * 128 + t];
        s += v.x; q += v.y;
    }
    const float invN = 1.f / (float)N_NODES;
    float mu  = s * invN;
    float var = q * invN - mu * mu;
    mu_out[t]  = mu;
    inv_out[t] = rsqrtf(var + BN_EPS);
}

// ---------------------------------------------------------------------------
// Tail finalize for the last layer (no aggregation, no xnext)
// ---------------------------------------------------------------------------
__global__ __launch_bounds__(256) void finalize_tail_kernel(
        const float* __restrict__ h,
        const float* __restrict__ mu_v, const float* __restrict__ inv_v,
        const float* __restrict__ gamma, const float* __restrict__ beta,
        const float* __restrict__ gumbel_l, const int* __restrict__ batch,
        float* __restrict__ nc_out, float* __restrict__ gc_out) {
    int lane = threadIdx.x & 63;
    int node = blockIdx.x * 4 + (threadIdx.x >> 6);

    float2 hv  = ((const float2*)h)[(size_t)node * 64 + lane];
    float2 mu2 = ((const float2*)mu_v)[lane];
    float2 iv2 = ((const float2*)inv_v)[lane];
    float2 g2  = ((const float2*)gamma)[lane];
    float2 be2 = ((const float2*)beta)[lane];
    float2 gm  = ((const float2*)gumbel_l)[(size_t)node * 64 + lane];

    float hb0 = (hv.x - mu2.x) * iv2.x * g2.x + be2.x;
    float hb1 = (hv.y - mu2.y) * iv2.y * g2.y + be2.y;
    float y0 = hb0 + gm.x;   // TAU == 1.0
    float y1 = hb1 + gm.y;

    float bv; int bi;
    if (y1 > y0) { bv = y1; bi = 2 * lane + 1; }
    else         { bv = y0; bi = 2 * lane; }
    #pragma unroll
    for (int off = 32; off > 0; off >>= 1) {
        float ov = __shfl_xor(bv, off);
        int   oi = __shfl_xor(bi, off);
        if (ov > bv || (ov == bv && oi < bi)) { bv = ov; bi = oi; }
    }

    float2 nc;
    nc.x = (bi == 2 * lane)     ? 1.0f : 0.0f;
    nc.y = (bi == 2 * lane + 1) ? 1.0f : 0.0f;
    ((float2*)nc_out)[(size_t)node * 64 + lane] = nc;

    if (lane == 0) atomicExch(&gc_out[(size_t)batch[node] * EMB + bi], 1.0f);
}

// ---------------------------------------------------------------------------
// logits = gc_last @ dense_W + dense_b
// ---------------------------------------------------------------------------
__global__ __launch_bounds__(128) void logits_kernel(
        const float* __restrict__ gc, const float* __restrict__ W,
        const float* __restrict__ b, float* __restrict__ out) {
    __shared__ float row[EMB];
    int g = blockIdx.x;
    int t = threadIdx.x;
    row[t] = gc[g * EMB + t];
    __syncthreads();
    if (t < N_CLASSES) {
        float acc = b[t];
        for (int k = 0; k < EMB; ++k) acc += row[k] * W[k * N_CLASSES + t];
        out[g * N_CLASSES + t] = acc;
    }
}

// ---------------------------------------------------------------------------
extern "C" void kernel_launch(void* const* d_in, const int* in_sizes, int n_in,
                              void* d_out, int out_size, void* d_ws, size_t ws_size,
                              hipStream_t stream) {
    const float* x_in    = (const float*)d_in[0];
    const int*   ei      = (const int*)  d_in[1];
    const int*   batch   = (const int*)  d_in[2];
    const float* W1      = (const float*)d_in[3];
    const float* b1      = (const float*)d_in[4];
    const float* W2      = (const float*)d_in[5];
    const float* b2      = (const float*)d_in[6];
    const float* gamma   = (const float*)d_in[7];
    const float* beta    = (const float*)d_in[8];
    const float* gumbel  = (const float*)d_in[9];
    const float* dW      = (const float*)d_in[10];
    const float* db      = (const float*)d_in[11];

    float* out = (float*)d_out;
    const size_t NC_OFF = (size_t)N_GRAPHS * N_CLASSES;
    const size_t GC_OFF = NC_OFF + (size_t)L_LAYERS * N_NODES * EMB;
    float* logits_out = out;
    float* nc_out     = out + NC_OFF;
    float* gc_out     = out + GC_OFF;

    // workspace layout
    float* bufA    = (float*)d_ws;                    // 6.4M floats
    float* bufB    = bufA + (size_t)N_NODES * EMB;    // 6.4M floats
    float* pstat   = bufB + (size_t)N_NODES * EMB;    // NBLK*256 (sum/sq interleaved)
    float* mu_v    = pstat + (size_t)NBLK * 256;      // 128
    float* inv_v   = mu_v + EMB;                      // 128
    int*   rowptr  = (int*)(inv_v + EMB);             // 50001
    int*   cursor  = rowptr + (N_NODES + 1);          // 50000
    int*   csr     = cursor + N_NODES;                // 800000
    int*   deg     = csr + N_EDGES;                   // 50000

    // CSR build (deterministic after per-node sort)
    hipMemsetAsync(deg, 0, N_NODES * sizeof(int), stream);
    deg_kernel<<<(N_EDGES + 255) / 256, 256, 0, stream>>>(ei, deg);
    scan_kernel<<<1, 256, 0, stream>>>(deg, rowptr, cursor);
    scatter_kernel<<<(N_EDGES + 255) / 256, 256, 0, stream>>>(ei, cursor, csr);
    sort_adj_kernel<<<(N_NODES + 255) / 256, 256, 0, stream>>>(rowptr, csr);

    hipMemsetAsync(gc_out, 0,
                   (size_t)L_LAYERS * N_GRAPHS * EMB * sizeof(float), stream);

    float* buf[2] = { bufA, bufB };

    // layer 0: raw aggregate from x_in
    agg_kernel<<<(N_NODES + 3) / 4, 256, 0, stream>>>(x_in, rowptr, csr, bufA);
    mlp_kernel<<<NBLK, 256, 0, stream>>>(bufA, W1, b1, W2, b2, pstat);
    bn_stats_kernel<<<1, 128, 0, stream>>>(pstat, mu_v, inv_v);

    for (int l = 1; l < L_LAYERS; ++l) {
        float* hprev = buf[(l - 1) & 1];
        float* hcur  = buf[l & 1];
        gather_fin_kernel<<<(N_NODES + 3) / 4, 256, 0, stream>>>(
            hprev, mu_v, inv_v,
            gamma + (size_t)(l - 1) * EMB, beta + (size_t)(l - 1) * EMB,
            gumbel + (size_t)(l - 1) * N_NODES * EMB, batch,
            rowptr, csr,
            nc_out + (size_t)(l - 1) * N_NODES * EMB,
            gc_out + (size_t)(l - 1) * N_GRAPHS * EMB,
            hcur);
        mlp_kernel<<<NBLK, 256, 0, stream>>>(
            hcur,
            W1 + (size_t)l * EMB * EMB, b1 + (size_t)l * EMB,
            W2 + (size_t)l * EMB * EMB, b2 + (size_t)l * EMB,
            pstat);
        bn_stats_kernel<<<1, 128, 0, stream>>>(pstat, mu_v, inv_v);
    }

    // finalize last layer (no aggregation)
    finalize_tail_kernel<<<(N_NODES + 3) / 4, 256, 0, stream>>>(
        buf[(L_LAYERS - 1) & 1], mu_v, inv_v,
        gamma + (size_t)(L_LAYERS - 1) * EMB, beta + (size_t)(L_LAYERS - 1) * EMB,
        gumbel + (size_t)(L_LAYERS - 1) * N_NODES * EMB, batch,
        nc_out + (size_t)(L_LAYERS - 1) * N_NODES * EMB,
        gc_out + (size_t)(L_LAYERS - 1) * N_GRAPHS * EMB);

    logits_kernel<<<N_GRAPHS, 128, 0, stream>>>(
        gc_out + (size_t)(L_LAYERS - 1) * N_GRAPHS * EMB, dW, db, logits_out);
}

// Round 5
// 1766.393 us; speedup vs baseline: 1.2567x; 1.0457x over previous
//
#include <hip/hip_runtime.h>

#define N_NODES   50000
#define N_EDGES   800000
#define N_GRAPHS  256
#define EMB       128
#define L_LAYERS  8
#define N_CLASSES 10
#define BN_EPS    1e-5f
#define NEG_SLOPE 0.01f
#define BM 128
#define NBLK ((N_NODES + BM - 1) / BM)   // 391 mlp blocks

// ---------------------------------------------------------------------------
// CSR build
// ---------------------------------------------------------------------------
__global__ void deg_kernel(const int* __restrict__ ei, int* __restrict__ deg) {
    int e = blockIdx.x * 256 + threadIdx.x;
    if (e < N_EDGES) atomicAdd(&deg[ei[N_EDGES + e]], 1);
}

__global__ void scan_kernel(const int* __restrict__ deg,
                            int* __restrict__ rowptr, int* __restrict__ cursor) {
    __shared__ int sums[256];
    __shared__ int offs[257];
    int t = threadIdx.x;
    const int chunk = (N_NODES + 255) / 256;  // 196
    int start = t * chunk;
    int end   = start + chunk; if (end > N_NODES) end = N_NODES;
    int s = 0;
    for (int i = start; i < end; ++i) s += deg[i];
    sums[t] = s;
    __syncthreads();
    if (t == 0) {
        int a = 0;
        for (int i = 0; i < 256; ++i) { offs[i] = a; a += sums[i]; }
        offs[256] = a;
    }
    __syncthreads();
    int a = offs[t];
    for (int i = start; i < end; ++i) {
        rowptr[i] = a; cursor[i] = a; a += deg[i];
    }
    if (t == 255) rowptr[N_NODES] = offs[256];
}

__global__ void scatter_kernel(const int* __restrict__ ei,
                               int* __restrict__ cursor, int* __restrict__ csr) {
    int e = blockIdx.x * 256 + threadIdx.x;
    if (e < N_EDGES) {
        int d = ei[N_EDGES + e];
        int s = ei[e];
        int p = atomicAdd(&cursor[d], 1);
        csr[p] = s;
    }
}

// Deterministic adjacency: sort each node's neighbor list.
__global__ void sort_adj_kernel(const int* __restrict__ rowptr, int* __restrict__ csr) {
    int node = blockIdx.x * 256 + threadIdx.x;
    if (node >= N_NODES) return;
    int beg = rowptr[node];
    int end = rowptr[node + 1];
    for (int i = beg + 1; i < end; ++i) {
        int v = csr[i];
        int j = i - 1;
        while (j >= beg && csr[j] > v) { csr[j + 1] = csr[j]; --j; }
        csr[j + 1] = v;
    }
}

// ---------------------------------------------------------------------------
// Layer-0 GIN aggregate: hpre[i] = x[i] + sum_{j->i} x[j]  (raw x, csr order)
// ---------------------------------------------------------------------------
__global__ __launch_bounds__(256) void agg_kernel(
        const float* __restrict__ x, const int* __restrict__ rowptr,
        const int* __restrict__ csr, float* __restrict__ hpre) {
    int lane = threadIdx.x & 63;
    int node = __builtin_amdgcn_readfirstlane(blockIdx.x * 4 + (threadIdx.x >> 6));
    if (node >= N_NODES) return;
    int beg = rowptr[node];
    int end = rowptr[node + 1];
    const float2* xp = (const float2*)x;
    float2 acc = xp[(size_t)node * 64 + lane];
    int e = beg;
    for (; e + 3 < end; e += 4) {
        int s0 = csr[e];
        int s1 = csr[e + 1];
        int s2 = csr[e + 2];
        int s3 = csr[e + 3];
        float2 v0 = xp[(size_t)s0 * 64 + lane];
        float2 v1 = xp[(size_t)s1 * 64 + lane];
        float2 v2 = xp[(size_t)s2 * 64 + lane];
        float2 v3 = xp[(size_t)s3 * 64 + lane];
        acc.x += v0.x; acc.y += v0.y;   // keep exact sequential order
        acc.x += v1.x; acc.y += v1.y;
        acc.x += v2.x; acc.y += v2.y;
        acc.x += v3.x; acc.y += v3.y;
    }
    for (; e < end; ++e) {
        int s0 = csr[e];
        float2 v0 = xp[(size_t)s0 * 64 + lane];
        acc.x += v0.x; acc.y += v0.y;
    }
    ((float2*)hpre)[(size_t)node * 64 + lane] = acc;
}

// ---------------------------------------------------------------------------
// Fused finalize(layer l-1) + aggregate(layer l).
// ---------------------------------------------------------------------------
#define XFORM(hin, x0, x1)                                              \
    {                                                                   \
        float t0_ = (hin.x - mu2.x) * iv2.x * g2.x + be2.x;             \
        float t1_ = (hin.y - mu2.y) * iv2.y * g2.y + be2.y;             \
        x0 = (t0_ > 0.f) ? t0_ : NEG_SLOPE * t0_;                       \
        x1 = (t1_ > 0.f) ? t1_ : NEG_SLOPE * t1_;                       \
    }

__global__ __launch_bounds__(256) void gather_fin_kernel(
        const float* __restrict__ hprev,
        const float* __restrict__ mu_v, const float* __restrict__ inv_v,
        const float* __restrict__ gamma, const float* __restrict__ beta,
        const float* __restrict__ gumbel_l, const int* __restrict__ batch,
        const int* __restrict__ rowptr, const int* __restrict__ csr,
        float* __restrict__ nc_out, float* __restrict__ gc_out,
        float* __restrict__ hpre) {
    int lane = threadIdx.x & 63;
    int node = __builtin_amdgcn_readfirstlane(blockIdx.x * 4 + (threadIdx.x >> 6));
    if (node >= N_NODES) return;

    float2 mu2 = ((const float2*)mu_v)[lane];
    float2 iv2 = ((const float2*)inv_v)[lane];
    float2 g2  = ((const float2*)gamma)[lane];
    float2 be2 = ((const float2*)beta)[lane];

    const float2* hp = (const float2*)hprev;
    float2 hv = hp[(size_t)node * 64 + lane];
    float hb0 = (hv.x - mu2.x) * iv2.x * g2.x + be2.x;
    float hb1 = (hv.y - mu2.y) * iv2.y * g2.y + be2.y;

    // ---- finalize part (layer l-1): argmax(hb + gumbel), nc, gc ----
    {
        float2 gm = ((const float2*)gumbel_l)[(size_t)node * 64 + lane];
        float y0 = hb0 + gm.x;   // TAU == 1.0
        float y1 = hb1 + gm.y;
        float bv; int bi;
        if (y1 > y0) { bv = y1; bi = 2 * lane + 1; }
        else         { bv = y0; bi = 2 * lane; }
        #pragma unroll
        for (int off = 32; off > 0; off >>= 1) {
            float ov = __shfl_xor(bv, off);
            int   oi = __shfl_xor(bi, off);
            if (ov > bv || (ov == bv && oi < bi)) { bv = ov; bi = oi; }
        }
        float2 nc;
        nc.x = (bi == 2 * lane)     ? 1.0f : 0.0f;
        nc.y = (bi == 2 * lane + 1) ? 1.0f : 0.0f;
        ((float2*)nc_out)[(size_t)node * 64 + lane] = nc;
        if (lane == 0) atomicExch(&gc_out[(size_t)batch[node] * EMB + bi], 1.0f);
    }

    // ---- aggregate part (layer l): acc = x[node] + sum x[nbr], csr order ----
    float2 acc;
    acc.x = (hb0 > 0.f) ? hb0 : NEG_SLOPE * hb0;
    acc.y = (hb1 > 0.f) ? hb1 : NEG_SLOPE * hb1;

    int beg = rowptr[node];
    int end = rowptr[node + 1];
    int e = beg;
    for (; e + 3 < end; e += 4) {
        int s0 = csr[e];
        int s1 = csr[e + 1];
        int s2 = csr[e + 2];
        int s3 = csr[e + 3];
        float2 h0 = hp[(size_t)s0 * 64 + lane];
        float2 h1 = hp[(size_t)s1 * 64 + lane];
        float2 h2 = hp[(size_t)s2 * 64 + lane];
        float2 h3 = hp[(size_t)s3 * 64 + lane];
        float a0, b0v, a1, b1v, a2, b2v, a3, b3v;
        XFORM(h0, a0, b0v)
        XFORM(h1, a1, b1v)
        XFORM(h2, a2, b2v)
        XFORM(h3, a3, b3v)
        acc.x += a0; acc.y += b0v;   // keep exact sequential order
        acc.x += a1; acc.y += b1v;
        acc.x += a2; acc.y += b2v;
        acc.x += a3; acc.y += b3v;
    }
    for (; e < end; ++e) {
        int s0 = csr[e];
        float2 h0 = hp[(size_t)s0 * 64 + lane];
        float a0, b0v;
        XFORM(h0, a0, b0v)
        acc.x += a0; acc.y += b0v;
    }
    ((float2*)hpre)[(size_t)node * 64 + lane] = acc;
}

// ---------------------------------------------------------------------------
// Fused MLP, wave-column structure, 2 rows per lane (BM = 128):
//   lane handles rows {lane, lane+64}; wave owns column strip wid*32..+31.
// W/b accesses are wave-uniform -> scalar s_load; 2x FMAs per scalar byte
// vs the BM=64 version. K-loop LDS traffic: 2 ds_read_b128 per 4 k-steps.
// Per-output accumulation is strict k=0..127 ascending.
// ---------------------------------------------------------------------------
__global__ __launch_bounds__(256) void mlp_kernel(
        float* __restrict__ HB,
        const float* __restrict__ W1, const float* __restrict__ b1,
        const float* __restrict__ W2, const float* __restrict__ b2,
        float* __restrict__ pstat) {
    __shared__ float As[BM][EMB + 4];   // 128 x 132 = 67.6 KB

    const int t    = threadIdx.x;
    const int lane = t & 63;
    const int wid  = __builtin_amdgcn_readfirstlane(t >> 6);
    const int wcol = wid * 32;
    const int row0 = blockIdx.x * BM;

    // ---- stage A tile (row-major, zero-padded tail rows) ----
    {
        const float4* Ag = (const float4*)HB;
        #pragma unroll
        for (int rep = 0; rep < 16; ++rep) {
            int v  = t + rep * 256;
            int r  = v >> 5;
            int c4 = v & 31;
            int gr = row0 + r;
            float4 val = (gr < N_NODES) ? Ag[(size_t)gr * 32 + c4]
                                        : make_float4(0.f, 0.f, 0.f, 0.f);
            *(float4*)&As[r][c4 * 4] = val;
        }
    }
    __syncthreads();

    float acc0[32], acc1[32];
    #pragma unroll
    for (int j = 0; j < 32; ++j) { acc0[j] = 0.f; acc1[j] = 0.f; }

    // ---- phase 1: acc = A(rows) @ W1(:, wcol..wcol+31), k ascending ----
    {
        const float* Wb = W1 + wcol;
        #pragma unroll 2
        for (int k4 = 0; k4 < 32; ++k4) {
            float4 a4 = *(const float4*)&As[lane][k4 * 4];
            float4 c4 = *(const float4*)&As[lane + 64][k4 * 4];
            const float* wk = Wb + (size_t)(k4 * 4) * EMB;
            #pragma unroll
            for (int dk = 0; dk < 4; ++dk) {
                float a = (dk == 0) ? a4.x : (dk == 1) ? a4.y
                         : (dk == 2) ? a4.z : a4.w;
                float c = (dk == 0) ? c4.x : (dk == 1) ? c4.y
                         : (dk == 2) ? c4.z : c4.w;
                const float* w = wk + (size_t)dk * EMB;
                #pragma unroll
                for (int j = 0; j < 32; ++j) {
                    acc0[j] += a * w[j];
                    acc1[j] += c * w[j];
                }
            }
        }
    }

    __syncthreads();   // all phase-1 reads of As done before T overwrites it

    // ---- transform: T = leaky(acc + b1), write back to As rows ----
    #pragma unroll
    for (int q = 0; q < 8; ++q) {
        float4 o0, o1;
        #pragma unroll
        for (int i = 0; i < 4; ++i) {
            float bias = b1[wcol + q * 4 + i];
            float v0 = acc0[q * 4 + i] + bias;
            float v1 = acc1[q * 4 + i] + bias;
            v0 = (v0 > 0.f) ? v0 : NEG_SLOPE * v0;
            v1 = (v1 > 0.f) ? v1 : NEG_SLOPE * v1;
            (&o0.x)[i] = v0;
            (&o1.x)[i] = v1;
            acc0[q * 4 + i] = 0.f;
            acc1[q * 4 + i] = 0.f;
        }
        *(float4*)&As[lane][wcol + q * 4]      = o0;
        *(float4*)&As[lane + 64][wcol + q * 4] = o1;
    }
    __syncthreads();   // T visible to all waves

    // ---- phase 2: acc = T(rows) @ W2(:, wcol..wcol+31), k ascending ----
    {
        const float* Wb = W2 + wcol;
        #pragma unroll 2
        for (int k4 = 0; k4 < 32; ++k4) {
            float4 a4 = *(const float4*)&As[lane][k4 * 4];
            float4 c4 = *(const float4*)&As[lane + 64][k4 * 4];
            const float* wk = Wb + (size_t)(k4 * 4) * EMB;
            #pragma unroll
            for (int dk = 0; dk < 4; ++dk) {
                float a = (dk == 0) ? a4.x : (dk == 1) ? a4.y
                         : (dk == 2) ? a4.z : a4.w;
                float c = (dk == 0) ? c4.x : (dk == 1) ? c4.y
                         : (dk == 2) ? c4.z : c4.w;
                const float* w = wk + (size_t)dk * EMB;
                #pragma unroll
                for (int j = 0; j < 32; ++j) {
                    acc0[j] += a * w[j];
                    acc1[j] += c * w[j];
                }
            }
        }
    }

    // ---- epilogue: h = acc + b2 (in place), store to global ----
    #pragma unroll
    for (int j = 0; j < 32; ++j) {
        float bias = b2[wcol + j];
        acc0[j] += bias;
        acc1[j] += bias;
    }
    const int gr0 = row0 + lane;
    const int gr1 = row0 + 64 + lane;
    if (gr0 < N_NODES) {
        #pragma unroll
        for (int q = 0; q < 8; ++q)
            *(float4*)&HB[(size_t)gr0 * EMB + wcol + q * 4] =
                make_float4(acc0[q * 4 + 0], acc0[q * 4 + 1],
                            acc0[q * 4 + 2], acc0[q * 4 + 3]);
    }
    if (gr1 < N_NODES) {
        #pragma unroll
        for (int q = 0; q < 8; ++q)
            *(float4*)&HB[(size_t)gr1 * EMB + wcol + q * 4] =
                make_float4(acc1[q * 4 + 0], acc1[q * 4 + 1],
                            acc1[q * 4 + 2], acc1[q * 4 + 3]);
    }

    // ---- stash h in LDS, per-block BN partials (ascending-row order) ----
    __syncthreads();   // all phase-2 reads of As done before h overwrites it
    #pragma unroll
    for (int q = 0; q < 8; ++q) {
        *(float4*)&As[lane][wcol + q * 4] =
            make_float4(acc0[q * 4 + 0], acc0[q * 4 + 1],
                        acc0[q * 4 + 2], acc0[q * 4 + 3]);
        *(float4*)&As[lane + 64][wcol + q * 4] =
            make_float4(acc1[q * 4 + 0], acc1[q * 4 + 1],
                        acc1[q * 4 + 2], acc1[q * 4 + 3]);
    }
    __syncthreads();

    if (t < EMB) {
        int valid = N_NODES - row0; if (valid > BM) valid = BM;
        float s = 0.f, q = 0.f;
        for (int r = 0; r < valid; ++r) {
            float v = As[r][t];
            s += v;
            q += v * v;
        }
        float2 o; o.x = s; o.y = q;
        *(float2*)&pstat[(size_t)blockIdx.x * 256 + 2 * t] = o;
    }
}

// ---------------------------------------------------------------------------
// Per-block partials -> mu / inv. 1024 threads: 8 b-chunks x 128 columns,
// strict ascending order within chunks and ascending-chunk combine
// (fixed deterministic grouping).
// ---------------------------------------------------------------------------
__global__ __launch_bounds__(1024) void bn_stats_kernel(
        const float* __restrict__ pstat,
        float* __restrict__ mu_out, float* __restrict__ inv_out) {
    __shared__ float2 part[8][128];
    int t   = threadIdx.x;
    int col = t & 127;
    int ch  = t >> 7;
    const int CH = (NBLK + 7) / 8;   // 49
    int b  = ch * CH;
    int be = b + CH; if (be > NBLK) be = NBLK;
    const float2* p = (const float2*)pstat;  // [b][128] float2
    float s = 0.f, q = 0.f;
    for (; b + 4 <= be; b += 4) {
        float2 v0 = p[(size_t)(b + 0) * 128 + col];
        float2 v1 = p[(size_t)(b + 1) * 128 + col];
        float2 v2 = p[(size_t)(b + 2) * 128 + col];
        float2 v3 = p[(size_t)(b + 3) * 128 + col];
        s += v0.x; q += v0.y;
        s += v1.x; q += v1.y;
        s += v2.x; q += v2.y;
        s += v3.x; q += v3.y;
    }
    for (; b < be; ++b) {
        float2 v = p[(size_t)b * 128 + col];
        s += v.x; q += v.y;
    }
    float2 o; o.x = s; o.y = q;
    part[ch][col] = o;
    __syncthreads();
    if (t < 128) {
        float S = 0.f, Q = 0.f;
        #pragma unroll
        for (int c = 0; c < 8; ++c) {   // ascending chunk order
            float2 v = part[c][t];
            S += v.x; Q += v.y;
        }
        const float invN = 1.f / (float)N_NODES;
        float mu  = S * invN;
        float var = Q * invN - mu * mu;
        mu_out[t]  = mu;
        inv_out[t] = rsqrtf(var + BN_EPS);
    }
}

// ---------------------------------------------------------------------------
// Tail finalize for the last layer (no aggregation, no xnext)
// ---------------------------------------------------------------------------
__global__ __launch_bounds__(256) void finalize_tail_kernel(
        const float* __restrict__ h,
        const float* __restrict__ mu_v, const float* __restrict__ inv_v,
        const float* __restrict__ gamma, const float* __restrict__ beta,
        const float* __restrict__ gumbel_l, const int* __restrict__ batch,
        float* __restrict__ nc_out, float* __restrict__ gc_out) {
    int lane = threadIdx.x & 63;
    int node = blockIdx.x * 4 + (threadIdx.x >> 6);

    float2 hv  = ((const float2*)h)[(size_t)node * 64 + lane];
    float2 mu2 = ((const float2*)mu_v)[lane];
    float2 iv2 = ((const float2*)inv_v)[lane];
    float2 g2  = ((const float2*)gamma)[lane];
    float2 be2 = ((const float2*)beta)[lane];
    float2 gm  = ((const float2*)gumbel_l)[(size_t)node * 64 + lane];

    float hb0 = (hv.x - mu2.x) * iv2.x * g2.x + be2.x;
    float hb1 = (hv.y - mu2.y) * iv2.y * g2.y + be2.y;
    float y0 = hb0 + gm.x;   // TAU == 1.0
    float y1 = hb1 + gm.y;

    float bv; int bi;
    if (y1 > y0) { bv = y1; bi = 2 * lane + 1; }
    else         { bv = y0; bi = 2 * lane; }
    #pragma unroll
    for (int off = 32; off > 0; off >>= 1) {
        float ov = __shfl_xor(bv, off);
        int   oi = __shfl_xor(bi, off);
        if (ov > bv || (ov == bv && oi < bi)) { bv = ov; bi = oi; }
    }

    float2 nc;
    nc.x = (bi == 2 * lane)     ? 1.0f : 0.0f;
    nc.y = (bi == 2 * lane + 1) ? 1.0f : 0.0f;
    ((float2*)nc_out)[(size_t)node * 64 + lane] = nc;

    if (lane == 0) atomicExch(&gc_out[(size_t)batch[node] * EMB + bi], 1.0f);
}

// ---------------------------------------------------------------------------
// logits = gc_last @ dense_W + dense_b
// ---------------------------------------------------------------------------
__global__ __launch_bounds__(128) void logits_kernel(
        const float* __restrict__ gc, const float* __restrict__ W,
        const float* __restrict__ b, float* __restrict__ out) {
    __shared__ float row[EMB];
    int g = blockIdx.x;
    int t = threadIdx.x;
    row[t] = gc[g * EMB + t];
    __syncthreads();
    if (t < N_CLASSES) {
        float acc = b[t];
        for (int k = 0; k < EMB; ++k) acc += row[k] * W[k * N_CLASSES + t];
        out[g * N_CLASSES + t] = acc;
    }
}

// ---------------------------------------------------------------------------
extern "C" void kernel_launch(void* const* d_in, const int* in_sizes, int n_in,
                              void* d_out, int out_size, void* d_ws, size_t ws_size,
                              hipStream_t stream) {
    const float* x_in    = (const float*)d_in[0];
    const int*   ei      = (const int*)  d_in[1];
    const int*   batch   = (const int*)  d_in[2];
    const float* W1      = (const float*)d_in[3];
    const float* b1      = (const float*)d_in[4];
    const float* W2      = (const float*)d_in[5];
    const float* b2      = (const float*)d_in[6];
    const float* gamma   = (const float*)d_in[7];
    const float* beta    = (const float*)d_in[8];
    const float* gumbel  = (const float*)d_in[9];
    const float* dW      = (const float*)d_in[10];
    const float* db      = (const float*)d_in[11];

    float* out = (float*)d_out;
    const size_t NC_OFF = (size_t)N_GRAPHS * N_CLASSES;
    const size_t GC_OFF = NC_OFF + (size_t)L_LAYERS * N_NODES * EMB;
    float* logits_out = out;
    float* nc_out     = out + NC_OFF;
    float* gc_out     = out + GC_OFF;

    // workspace layout
    float* bufA    = (float*)d_ws;                    // 6.4M floats
    float* bufB    = bufA + (size_t)N_NODES * EMB;    // 6.4M floats
    float* pstat   = bufB + (size_t)N_NODES * EMB;    // NBLK*256 (sum/sq interleaved)
    float* mu_v    = pstat + (size_t)NBLK * 256;      // 128
    float* inv_v   = mu_v + EMB;                      // 128
    int*   rowptr  = (int*)(inv_v + EMB);             // 50001
    int*   cursor  = rowptr + (N_NODES + 1);          // 50000
    int*   csr     = cursor + N_NODES;                // 800000
    int*   deg     = csr + N_EDGES;                   // 50000

    // CSR build (deterministic after per-node sort)
    hipMemsetAsync(deg, 0, N_NODES * sizeof(int), stream);
    deg_kernel<<<(N_EDGES + 255) / 256, 256, 0, stream>>>(ei, deg);
    scan_kernel<<<1, 256, 0, stream>>>(deg, rowptr, cursor);
    scatter_kernel<<<(N_EDGES + 255) / 256, 256, 0, stream>>>(ei, cursor, csr);
    sort_adj_kernel<<<(N_NODES + 255) / 256, 256, 0, stream>>>(rowptr, csr);

    hipMemsetAsync(gc_out, 0,
                   (size_t)L_LAYERS * N_GRAPHS * EMB * sizeof(float), stream);

    float* buf[2] = { bufA, bufB };

    // layer 0: raw aggregate from x_in
    agg_kernel<<<(N_NODES + 3) / 4, 256, 0, stream>>>(x_in, rowptr, csr, bufA);
    mlp_kernel<<<NBLK, 256, 0, stream>>>(bufA, W1, b1, W2, b2, pstat);
    bn_stats_kernel<<<1, 1024, 0, stream>>>(pstat, mu_v, inv_v);

    for (int l = 1; l < L_LAYERS; ++l) {
        float* hprev = buf[(l - 1) & 1];
        float* hcur  = buf[l & 1];
        gather_fin_kernel<<<(N_NODES + 3) / 4, 256, 0, stream>>>(
            hprev, mu_v, inv_v,
            gamma + (size_t)(l - 1) * EMB, beta + (size_t)(l - 1) * EMB,
            gumbel + (size_t)(l - 1) * N_NODES * EMB, batch,
            rowptr, csr,
            nc_out + (size_t)(l - 1) * N_NODES * EMB,
            gc_out + (size_t)(l - 1) * N_GRAPHS * EMB,
            hcur);
        mlp_kernel<<<NBLK, 256, 0, stream>>>(
            hcur,
            W1 + (size_t)l * EMB * EMB, b1 + (size_t)l * EMB,
            W2 + (size_t)l * EMB * EMB, b2 + (size_t)l * EMB,
            pstat);
        bn_stats_kernel<<<1, 1024, 0, stream>>>(pstat, mu_v, inv_v);
    }

    // finalize last layer (no aggregation)
    finalize_tail_kernel<<<(N_NODES + 3) / 4, 256, 0, stream>>>(
        buf[(L_LAYERS - 1) & 1], mu_v, inv_v,
        gamma + (size_t)(L_LAYERS - 1) * EMB, beta + (size_t)(L_LAYERS - 1) * EMB,
        gumbel + (size_t)(L_LAYERS - 1) * N_NODES * EMB, batch,
        nc_out + (size_t)(L_LAYERS - 1) * N_NODES * EMB,
        gc_out + (size_t)(L_LAYERS - 1) * N_GRAPHS * EMB);

    logits_kernel<<<N_GRAPHS, 128, 0, stream>>>(
        gc_out + (size_t)(L_LAYERS - 1) * N_GRAPHS * EMB, dW, db, logits_out);
}

// Round 6
// 1675.397 us; speedup vs baseline: 1.3250x; 1.0543x over previous
//
#include <hip/hip_runtime.h>

#define N_NODES   50000
#define N_EDGES   800000
#define N_GRAPHS  256
#define EMB       128
#define L_LAYERS  8
#define N_CLASSES 10
#define BN_EPS    1e-5f
#define NEG_SLOPE 0.01f
#define BM 128
#define NBLK ((N_NODES + BM - 1) / BM)   // 391 mlp blocks

// ---------------------------------------------------------------------------
// CSR build
// ---------------------------------------------------------------------------
__global__ void deg_kernel(const int* __restrict__ ei, int* __restrict__ deg) {
    int e = blockIdx.x * 256 + threadIdx.x;
    if (e < N_EDGES) atomicAdd(&deg[ei[N_EDGES + e]], 1);
}

// 1024-thread parallel exclusive scan: per-thread 49-chunk sum (ILP loads),
// 64-lane shuffle scan + 16-wave LDS combine, then per-thread prefix write.
// Integer arithmetic => exact, same rowptr/cursor bits as the serial version.
__global__ __launch_bounds__(1024) void scan_kernel(
        const int* __restrict__ deg,
        int* __restrict__ rowptr, int* __restrict__ cursor) {
    __shared__ int wsum[16];
    int t = threadIdx.x;
    int lane = t & 63;
    int w = t >> 6;
    const int chunk = (N_NODES + 1023) / 1024;  // 49
    int start = t * chunk;
    int end = start + chunk; if (end > N_NODES) end = N_NODES;
    int s = 0;
    for (int i = start; i < end; ++i) s += deg[i];
    // inclusive wave scan
    int v = s;
    #pragma unroll
    for (int off = 1; off < 64; off <<= 1) {
        int o = __shfl_up(v, off);
        if (lane >= off) v += o;
    }
    if (lane == 63) wsum[w] = v;
    __syncthreads();
    if (w == 0 && lane < 16) {
        int x = wsum[lane];
        #pragma unroll
        for (int off = 1; off < 16; off <<= 1) {
            int o = __shfl_up(x, off);
            if (lane >= off) x += o;
        }
        wsum[lane] = x;   // inclusive across waves
    }
    __syncthreads();
    int base = (w > 0 ? wsum[w - 1] : 0) + (v - s);  // exclusive prefix
    int a = base;
    for (int i = start; i < end; ++i) {
        rowptr[i] = a; cursor[i] = a; a += deg[i];
    }
    if (t == 0) rowptr[N_NODES] = wsum[15];
}

__global__ void scatter_kernel(const int* __restrict__ ei,
                               int* __restrict__ cursor, int* __restrict__ csr) {
    int e = blockIdx.x * 256 + threadIdx.x;
    if (e < N_EDGES) {
        int d = ei[N_EDGES + e];
        int s = ei[e];
        int p = atomicAdd(&cursor[d], 1);
        csr[p] = s;
    }
}

// Deterministic adjacency: ascending sort of each node's neighbor list.
// Wave-per-node 64-lane bitonic sort (same multiset -> bitwise-identical
// sorted array as insertion sort, independent of atomic arrival order).
// Degree > 64 (never for this dataset) falls back to serial insertion.
__global__ __launch_bounds__(256) void sort_adj_kernel(
        const int* __restrict__ rowptr, int* __restrict__ csr) {
    int lane = threadIdx.x & 63;
    int node = blockIdx.x * 4 + (threadIdx.x >> 6);
    if (node >= N_NODES) return;
    int beg = rowptr[node];
    int end = rowptr[node + 1];
    int d = end - beg;
    if (d <= 1) return;
    if (d <= 64) {
        int v = (lane < d) ? csr[beg + lane] : 0x7fffffff;
        #pragma unroll
        for (int k = 2; k <= 64; k <<= 1) {
            #pragma unroll
            for (int j = k >> 1; j > 0; j >>= 1) {
                int other = __shfl_xor(v, j);
                bool up    = ((lane & k) == 0);
                bool lower = ((lane & j) == 0);
                int mn = (v < other) ? v : other;
                int mx = (v < other) ? other : v;
                v = (up == lower) ? mn : mx;
            }
        }
        if (lane < d) csr[beg + lane] = v;
    } else if (lane == 0) {
        for (int i = beg + 1; i < end; ++i) {
            int vv = csr[i];
            int j = i - 1;
            while (j >= beg && csr[j] > vv) { csr[j + 1] = csr[j]; --j; }
            csr[j + 1] = vv;
        }
    }
}

// ---------------------------------------------------------------------------
// Layer-0 GIN aggregate: hpre[i] = x[i] + sum_{j->i} x[j]  (raw x, csr order)
// ---------------------------------------------------------------------------
__global__ __launch_bounds__(256) void agg_kernel(
        const float* __restrict__ x, const int* __restrict__ rowptr,
        const int* __restrict__ csr, float* __restrict__ hpre) {
    int lane = threadIdx.x & 63;
    int node = __builtin_amdgcn_readfirstlane(blockIdx.x * 4 + (threadIdx.x >> 6));
    if (node >= N_NODES) return;
    int beg = rowptr[node];
    int end = rowptr[node + 1];
    const float2* xp = (const float2*)x;
    float2 acc = xp[(size_t)node * 64 + lane];
    int e = beg;
    for (; e + 3 < end; e += 4) {
        int s0 = csr[e];
        int s1 = csr[e + 1];
        int s2 = csr[e + 2];
        int s3 = csr[e + 3];
        float2 v0 = xp[(size_t)s0 * 64 + lane];
        float2 v1 = xp[(size_t)s1 * 64 + lane];
        float2 v2 = xp[(size_t)s2 * 64 + lane];
        float2 v3 = xp[(size_t)s3 * 64 + lane];
        acc.x += v0.x; acc.y += v0.y;   // keep exact sequential order
        acc.x += v1.x; acc.y += v1.y;
        acc.x += v2.x; acc.y += v2.y;
        acc.x += v3.x; acc.y += v3.y;
    }
    for (; e < end; ++e) {
        int s0 = csr[e];
        float2 v0 = xp[(size_t)s0 * 64 + lane];
        acc.x += v0.x; acc.y += v0.y;
    }
    ((float2*)hpre)[(size_t)node * 64 + lane] = acc;
}

// ---------------------------------------------------------------------------
// Fused finalize(layer l-1) + aggregate(layer l).
// ---------------------------------------------------------------------------
#define XFORM(hin, x0, x1)                                              \
    {                                                                   \
        float t0_ = (hin.x - mu2.x) * iv2.x * g2.x + be2.x;             \
        float t1_ = (hin.y - mu2.y) * iv2.y * g2.y + be2.y;             \
        x0 = (t0_ > 0.f) ? t0_ : NEG_SLOPE * t0_;                       \
        x1 = (t1_ > 0.f) ? t1_ : NEG_SLOPE * t1_;                       \
    }

__global__ __launch_bounds__(256) void gather_fin_kernel(
        const float* __restrict__ hprev,
        const float* __restrict__ mu_v, const float* __restrict__ inv_v,
        const float* __restrict__ gamma, const float* __restrict__ beta,
        const float* __restrict__ gumbel_l, const int* __restrict__ batch,
        const int* __restrict__ rowptr, const int* __restrict__ csr,
        float* __restrict__ nc_out, float* __restrict__ gc_out,
        float* __restrict__ hpre) {
    int lane = threadIdx.x & 63;
    int node = __builtin_amdgcn_readfirstlane(blockIdx.x * 4 + (threadIdx.x >> 6));
    if (node >= N_NODES) return;

    float2 mu2 = ((const float2*)mu_v)[lane];
    float2 iv2 = ((const float2*)inv_v)[lane];
    float2 g2  = ((const float2*)gamma)[lane];
    float2 be2 = ((const float2*)beta)[lane];

    const float2* hp = (const float2*)hprev;
    float2 hv = hp[(size_t)node * 64 + lane];
    float hb0 = (hv.x - mu2.x) * iv2.x * g2.x + be2.x;
    float hb1 = (hv.y - mu2.y) * iv2.y * g2.y + be2.y;

    // ---- finalize part (layer l-1): argmax(hb + gumbel), nc, gc ----
    {
        float2 gm = ((const float2*)gumbel_l)[(size_t)node * 64 + lane];
        float y0 = hb0 + gm.x;   // TAU == 1.0
        float y1 = hb1 + gm.y;
        float bv; int bi;
        if (y1 > y0) { bv = y1; bi = 2 * lane + 1; }
        else         { bv = y0; bi = 2 * lane; }
        #pragma unroll
        for (int off = 32; off > 0; off >>= 1) {
            float ov = __shfl_xor(bv, off);
            int   oi = __shfl_xor(bi, off);
            if (ov > bv || (ov == bv && oi < bi)) { bv = ov; bi = oi; }
        }
        float2 nc;
        nc.x = (bi == 2 * lane)     ? 1.0f : 0.0f;
        nc.y = (bi == 2 * lane + 1) ? 1.0f : 0.0f;
        ((float2*)nc_out)[(size_t)node * 64 + lane] = nc;
        if (lane == 0) atomicExch(&gc_out[(size_t)batch[node] * EMB + bi], 1.0f);
    }

    // ---- aggregate part (layer l): acc = x[node] + sum x[nbr], csr order ----
    float2 acc;
    acc.x = (hb0 > 0.f) ? hb0 : NEG_SLOPE * hb0;
    acc.y = (hb1 > 0.f) ? hb1 : NEG_SLOPE * hb1;

    int beg = rowptr[node];
    int end = rowptr[node + 1];
    int e = beg;
    for (; e + 3 < end; e += 4) {
        int s0 = csr[e];
        int s1 = csr[e + 1];
        int s2 = csr[e + 2];
        int s3 = csr[e + 3];
        float2 h0 = hp[(size_t)s0 * 64 + lane];
        float2 h1 = hp[(size_t)s1 * 64 + lane];
        float2 h2 = hp[(size_t)s2 * 64 + lane];
        float2 h3 = hp[(size_t)s3 * 64 + lane];
        float a0, b0v, a1, b1v, a2, b2v, a3, b3v;
        XFORM(h0, a0, b0v)
        XFORM(h1, a1, b1v)
        XFORM(h2, a2, b2v)
        XFORM(h3, a3, b3v)
        acc.x += a0; acc.y += b0v;   // keep exact sequential order
        acc.x += a1; acc.y += b1v;
        acc.x += a2; acc.y += b2v;
        acc.x += a3; acc.y += b3v;
    }
    for (; e < end; ++e) {
        int s0 = csr[e];
        float2 h0 = hp[(size_t)s0 * 64 + lane];
        float a0, b0v;
        XFORM(h0, a0, b0v)
        acc.x += a0; acc.y += b0v;
    }
    ((float2*)hpre)[(size_t)node * 64 + lane] = acc;
}

// ---------------------------------------------------------------------------
// Fused MLP, wave-column structure, 2 rows per lane (BM = 128):
//   lane handles rows {lane, lane+64}; wave owns column strip wid*32..+31.
// W/b accesses are wave-uniform -> scalar s_load; 2x FMAs per scalar byte
// vs the BM=64 version. K-loop LDS traffic: 2 ds_read_b128 per 4 k-steps.
// Per-output accumulation is strict k=0..127 ascending.
// ---------------------------------------------------------------------------
__global__ __launch_bounds__(256) void mlp_kernel(
        float* __restrict__ HB,
        const float* __restrict__ W1, const float* __restrict__ b1,
        const float* __restrict__ W2, const float* __restrict__ b2,
        float* __restrict__ pstat) {
    __shared__ float As[BM][EMB + 4];   // 128 x 132 = 67.6 KB

    const int t    = threadIdx.x;
    const int lane = t & 63;
    const int wid  = __builtin_amdgcn_readfirstlane(t >> 6);
    const int wcol = wid * 32;
    const int row0 = blockIdx.x * BM;

    // ---- stage A tile (row-major, zero-padded tail rows) ----
    {
        const float4* Ag = (const float4*)HB;
        #pragma unroll
        for (int rep = 0; rep < 16; ++rep) {
            int v  = t + rep * 256;
            int r  = v >> 5;
            int c4 = v & 31;
            int gr = row0 + r;
            float4 val = (gr < N_NODES) ? Ag[(size_t)gr * 32 + c4]
                                        : make_float4(0.f, 0.f, 0.f, 0.f);
            *(float4*)&As[r][c4 * 4] = val;
        }
    }
    __syncthreads();

    float acc0[32], acc1[32];
    #pragma unroll
    for (int j = 0; j < 32; ++j) { acc0[j] = 0.f; acc1[j] = 0.f; }

    // ---- phase 1: acc = A(rows) @ W1(:, wcol..wcol+31), k ascending ----
    {
        const float* Wb = W1 + wcol;
        #pragma unroll 2
        for (int k4 = 0; k4 < 32; ++k4) {
            float4 a4 = *(const float4*)&As[lane][k4 * 4];
            float4 c4 = *(const float4*)&As[lane + 64][k4 * 4];
            const float* wk = Wb + (size_t)(k4 * 4) * EMB;
            #pragma unroll
            for (int dk = 0; dk < 4; ++dk) {
                float a = (dk == 0) ? a4.x : (dk == 1) ? a4.y
                         : (dk == 2) ? a4.z : a4.w;
                float c = (dk == 0) ? c4.x : (dk == 1) ? c4.y
                         : (dk == 2) ? c4.z : c4.w;
                const float* w = wk + (size_t)dk * EMB;
                #pragma unroll
                for (int j = 0; j < 32; ++j) {
                    acc0[j] += a * w[j];
                    acc1[j] += c * w[j];
                }
            }
        }
    }

    __syncthreads();   // all phase-1 reads of As done before T overwrites it

    // ---- transform: T = leaky(acc + b1), write back to As rows ----
    #pragma unroll
    for (int q = 0; q < 8; ++q) {
        float4 o0, o1;
        #pragma unroll
        for (int i = 0; i < 4; ++i) {
            float bias = b1[wcol + q * 4 + i];
            float v0 = acc0[q * 4 + i] + bias;
            float v1 = acc1[q * 4 + i] + bias;
            v0 = (v0 > 0.f) ? v0 : NEG_SLOPE * v0;
            v1 = (v1 > 0.f) ? v1 : NEG_SLOPE * v1;
            (&o0.x)[i] = v0;
            (&o1.x)[i] = v1;
            acc0[q * 4 + i] = 0.f;
            acc1[q * 4 + i] = 0.f;
        }
        *(float4*)&As[lane][wcol + q * 4]      = o0;
        *(float4*)&As[lane + 64][wcol + q * 4] = o1;
    }
    __syncthreads();   // T visible to all waves

    // ---- phase 2: acc = T(rows) @ W2(:, wcol..wcol+31), k ascending ----
    {
        const float* Wb = W2 + wcol;
        #pragma unroll 2
        for (int k4 = 0; k4 < 32; ++k4) {
            float4 a4 = *(const float4*)&As[lane][k4 * 4];
            float4 c4 = *(const float4*)&As[lane + 64][k4 * 4];
            const float* wk = Wb + (size_t)(k4 * 4) * EMB;
            #pragma unroll
            for (int dk = 0; dk < 4; ++dk) {
                float a = (dk == 0) ? a4.x : (dk == 1) ? a4.y
                         : (dk == 2) ? a4.z : a4.w;
                float c = (dk == 0) ? c4.x : (dk == 1) ? c4.y
                         : (dk == 2) ? c4.z : c4.w;
                const float* w = wk + (size_t)dk * EMB;
                #pragma unroll
                for (int j = 0; j < 32; ++j) {
                    acc0[j] += a * w[j];
                    acc1[j] += c * w[j];
                }
            }
        }
    }

    // ---- epilogue: h = acc + b2 (in place), store to global ----
    #pragma unroll
    for (int j = 0; j < 32; ++j) {
        float bias = b2[wcol + j];
        acc0[j] += bias;
        acc1[j] += bias;
    }
    const int gr0 = row0 + lane;
    const int gr1 = row0 + 64 + lane;
    if (gr0 < N_NODES) {
        #pragma unroll
        for (int q = 0; q < 8; ++q)
            *(float4*)&HB[(size_t)gr0 * EMB + wcol + q * 4] =
                make_float4(acc0[q * 4 + 0], acc0[q * 4 + 1],
                            acc0[q * 4 + 2], acc0[q * 4 + 3]);
    }
    if (gr1 < N_NODES) {
        #pragma unroll
        for (int q = 0; q < 8; ++q)
            *(float4*)&HB[(size_t)gr1 * EMB + wcol + q * 4] =
                make_float4(acc1[q * 4 + 0], acc1[q * 4 + 1],
                            acc1[q * 4 + 2], acc1[q * 4 + 3]);
    }

    // ---- stash h in LDS, per-block BN partials (ascending-row order) ----
    __syncthreads();   // all phase-2 reads of As done before h overwrites it
    #pragma unroll
    for (int q = 0; q < 8; ++q) {
        *(float4*)&As[lane][wcol + q * 4] =
            make_float4(acc0[q * 4 + 0], acc0[q * 4 + 1],
                        acc0[q * 4 + 2], acc0[q * 4 + 3]);
        *(float4*)&As[lane + 64][wcol + q * 4] =
            make_float4(acc1[q * 4 + 0], acc1[q * 4 + 1],
                        acc1[q * 4 + 2], acc1[q * 4 + 3]);
    }
    __syncthreads();

    if (t < EMB) {
        int valid = N_NODES - row0; if (valid > BM) valid = BM;
        float s = 0.f, q = 0.f;
        for (int r = 0; r < valid; ++r) {
            float v = As[r][t];
            s += v;
            q += v * v;
        }
        float2 o; o.x = s; o.y = q;
        *(float2*)&pstat[(size_t)blockIdx.x * 256 + 2 * t] = o;
    }
}

// ---------------------------------------------------------------------------
// Per-block partials -> mu / inv. 1024 threads: 8 b-chunks x 128 columns,
// strict ascending order within chunks and ascending-chunk combine
// (fixed deterministic grouping).
// ---------------------------------------------------------------------------
__global__ __launch_bounds__(1024) void bn_stats_kernel(
        const float* __restrict__ pstat,
        float* __restrict__ mu_out, float* __restrict__ inv_out) {
    __shared__ float2 part[8][128];
    int t   = threadIdx.x;
    int col = t & 127;
    int ch  = t >> 7;
    const int CH = (NBLK + 7) / 8;   // 49
    int b  = ch * CH;
    int be = b + CH; if (be > NBLK) be = NBLK;
    const float2* p = (const float2*)pstat;  // [b][128] float2
    float s = 0.f, q = 0.f;
    for (; b + 4 <= be; b += 4) {
        float2 v0 = p[(size_t)(b + 0) * 128 + col];
        float2 v1 = p[(size_t)(b + 1) * 128 + col];
        float2 v2 = p[(size_t)(b + 2) * 128 + col];
        float2 v3 = p[(size_t)(b + 3) * 128 + col];
        s += v0.x; q += v0.y;
        s += v1.x; q += v1.y;
        s += v2.x; q += v2.y;
        s += v3.x; q += v3.y;
    }
    for (; b < be; ++b) {
        float2 v = p[(size_t)b * 128 + col];
        s += v.x; q += v.y;
    }
    float2 o; o.x = s; o.y = q;
    part[ch][col] = o;
    __syncthreads();
    if (t < 128) {
        float S = 0.f, Q = 0.f;
        #pragma unroll
        for (int c = 0; c < 8; ++c) {   // ascending chunk order
            float2 v = part[c][t];
            S += v.x; Q += v.y;
        }
        const float invN = 1.f / (float)N_NODES;
        float mu  = S * invN;
        float var = Q * invN - mu * mu;
        mu_out[t]  = mu;
        inv_out[t] = rsqrtf(var + BN_EPS);
    }
}

// ---------------------------------------------------------------------------
// Tail finalize for the last layer (no aggregation, no xnext)
// ---------------------------------------------------------------------------
__global__ __launch_bounds__(256) void finalize_tail_kernel(
        const float* __restrict__ h,
        const float* __restrict__ mu_v, const float* __restrict__ inv_v,
        const float* __restrict__ gamma, const float* __restrict__ beta,
        const float* __restrict__ gumbel_l, const int* __restrict__ batch,
        float* __restrict__ nc_out, float* __restrict__ gc_out) {
    int lane = threadIdx.x & 63;
    int node = blockIdx.x * 4 + (threadIdx.x >> 6);

    float2 hv  = ((const float2*)h)[(size_t)node * 64 + lane];
    float2 mu2 = ((const float2*)mu_v)[lane];
    float2 iv2 = ((const float2*)inv_v)[lane];
    float2 g2  = ((const float2*)gamma)[lane];
    float2 be2 = ((const float2*)beta)[lane];
    float2 gm  = ((const float2*)gumbel_l)[(size_t)node * 64 + lane];

    float hb0 = (hv.x - mu2.x) * iv2.x * g2.x + be2.x;
    float hb1 = (hv.y - mu2.y) * iv2.y * g2.y + be2.y;
    float y0 = hb0 + gm.x;   // TAU == 1.0
    float y1 = hb1 + gm.y;

    float bv; int bi;
    if (y1 > y0) { bv = y1; bi = 2 * lane + 1; }
    else         { bv = y0; bi = 2 * lane; }
    #pragma unroll
    for (int off = 32; off > 0; off >>= 1) {
        float ov = __shfl_xor(bv, off);
        int   oi = __shfl_xor(bi, off);
        if (ov > bv || (ov == bv && oi < bi)) { bv = ov; bi = oi; }
    }

    float2 nc;
    nc.x = (bi == 2 * lane)     ? 1.0f : 0.0f;
    nc.y = (bi == 2 * lane + 1) ? 1.0f : 0.0f;
    ((float2*)nc_out)[(size_t)node * 64 + lane] = nc;

    if (lane == 0) atomicExch(&gc_out[(size_t)batch[node] * EMB + bi], 1.0f);
}

// ---------------------------------------------------------------------------
// logits = gc_last @ dense_W + dense_b
// ---------------------------------------------------------------------------
__global__ __launch_bounds__(128) void logits_kernel(
        const float* __restrict__ gc, const float* __restrict__ W,
        const float* __restrict__ b, float* __restrict__ out) {
    __shared__ float row[EMB];
    int g = blockIdx.x;
    int t = threadIdx.x;
    row[t] = gc[g * EMB + t];
    __syncthreads();
    if (t < N_CLASSES) {
        float acc = b[t];
        for (int k = 0; k < EMB; ++k) acc += row[k] * W[k * N_CLASSES + t];
        out[g * N_CLASSES + t] = acc;
    }
}

// ---------------------------------------------------------------------------
extern "C" void kernel_launch(void* const* d_in, const int* in_sizes, int n_in,
                              void* d_out, int out_size, void* d_ws, size_t ws_size,
                              hipStream_t stream) {
    const float* x_in    = (const float*)d_in[0];
    const int*   ei      = (const int*)  d_in[1];
    const int*   batch   = (const int*)  d_in[2];
    const float* W1      = (const float*)d_in[3];
    const float* b1      = (const float*)d_in[4];
    const float* W2      = (const float*)d_in[5];
    const float* b2      = (const float*)d_in[6];
    const float* gamma   = (const float*)d_in[7];
    const float* beta    = (const float*)d_in[8];
    const float* gumbel  = (const float*)d_in[9];
    const float* dW      = (const float*)d_in[10];
    const float* db      = (const float*)d_in[11];

    float* out = (float*)d_out;
    const size_t NC_OFF = (size_t)N_GRAPHS * N_CLASSES;
    const size_t GC_OFF = NC_OFF + (size_t)L_LAYERS * N_NODES * EMB;
    float* logits_out = out;
    float* nc_out     = out + NC_OFF;
    float* gc_out     = out + GC_OFF;

    // workspace layout
    float* bufA    = (float*)d_ws;                    // 6.4M floats
    float* bufB    = bufA + (size_t)N_NODES * EMB;    // 6.4M floats
    float* pstat   = bufB + (size_t)N_NODES * EMB;    // NBLK*256 (sum/sq interleaved)
    float* mu_v    = pstat + (size_t)NBLK * 256;      // 128
    float* inv_v   = mu_v + EMB;                      // 128
    int*   rowptr  = (int*)(inv_v + EMB);             // 50001
    int*   cursor  = rowptr + (N_NODES + 1);          // 50000
    int*   csr     = cursor + N_NODES;                // 800000
    int*   deg     = csr + N_EDGES;                   // 50000

    // CSR build (deterministic after per-node sort)
    hipMemsetAsync(deg, 0, N_NODES * sizeof(int), stream);
    deg_kernel<<<(N_EDGES + 255) / 256, 256, 0, stream>>>(ei, deg);
    scan_kernel<<<1, 1024, 0, stream>>>(deg, rowptr, cursor);
    scatter_kernel<<<(N_EDGES + 255) / 256, 256, 0, stream>>>(ei, cursor, csr);
    sort_adj_kernel<<<(N_NODES + 3) / 4, 256, 0, stream>>>(rowptr, csr);

    hipMemsetAsync(gc_out, 0,
                   (size_t)L_LAYERS * N_GRAPHS * EMB * sizeof(float), stream);

    float* buf[2] = { bufA, bufB };

    // layer 0: raw aggregate from x_in
    agg_kernel<<<(N_NODES + 3) / 4, 256, 0, stream>>>(x_in, rowptr, csr, bufA);
    mlp_kernel<<<NBLK, 256, 0, stream>>>(bufA, W1, b1, W2, b2, pstat);
    bn_stats_kernel<<<1, 1024, 0, stream>>>(pstat, mu_v, inv_v);

    for (int l = 1; l < L_LAYERS; ++l) {
        float* hprev = buf[(l - 1) & 1];
        float* hcur  = buf[l & 1];
        gather_fin_kernel<<<(N_NODES + 3) / 4, 256, 0, stream>>>(
            hprev, mu_v, inv_v,
            gamma + (size_t)(l - 1) * EMB, beta + (size_t)(l - 1) * EMB,
            gumbel + (size_t)(l - 1) * N_NODES * EMB, batch,
            rowptr, csr,
            nc_out + (size_t)(l - 1) * N_NODES * EMB,
            gc_out + (size_t)(l - 1) * N_GRAPHS * EMB,
            hcur);
        mlp_kernel<<<NBLK, 256, 0, stream>>>(
            hcur,
            W1 + (size_t)l * EMB * EMB, b1 + (size_t)l * EMB,
            W2 + (size_t)l * EMB * EMB, b2 + (size_t)l * EMB,
            pstat);
        bn_stats_kernel<<<1, 1024, 0, stream>>>(pstat, mu_v, inv_v);
    }

    // finalize last layer (no aggregation)
    finalize_tail_kernel<<<(N_NODES + 3) / 4, 256, 0, stream>>>(
        buf[(L_LAYERS - 1) & 1], mu_v, inv_v,
        gamma + (size_t)(L_LAYERS - 1) * EMB, beta + (size_t)(L_LAYERS - 1) * EMB,
        gumbel + (size_t)(L_LAYERS - 1) * N_NODES * EMB, batch,
        nc_out + (size_t)(L_LAYERS - 1) * N_NODES * EMB,
        gc_out + (size_t)(L_LAYERS - 1) * N_GRAPHS * EMB);

    logits_kernel<<<N_GRAPHS, 128, 0, stream>>>(
        gc_out + (size_t)(L_LAYERS - 1) * N_GRAPHS * EMB, dW, db, logits_out);
}

// Round 7
// 1461.216 us; speedup vs baseline: 1.5192x; 1.1466x over previous
//
#include <hip/hip_runtime.h>

#define N_NODES   50000
#define N_EDGES   800000
#define N_GRAPHS  256
#define EMB       128
#define L_LAYERS  8
#define N_CLASSES 10
#define BN_EPS    1e-5f
#define NEG_SLOPE 0.01f
#define BM 128
#define NBLK ((N_NODES + BM - 1) / BM)   // 391 mlp blocks

// ---------------------------------------------------------------------------
// CSR build
// ---------------------------------------------------------------------------
__global__ void deg_kernel(const int* __restrict__ ei, int* __restrict__ deg) {
    int e = blockIdx.x * 256 + threadIdx.x;
    if (e < N_EDGES) atomicAdd(&deg[ei[N_EDGES + e]], 1);
}

// 1024-thread parallel exclusive scan: per-thread 49-chunk sum (ILP loads),
// 64-lane shuffle scan + 16-wave LDS combine, then per-thread prefix write.
__global__ __launch_bounds__(1024) void scan_kernel(
        const int* __restrict__ deg,
        int* __restrict__ rowptr, int* __restrict__ cursor) {
    __shared__ int wsum[16];
    int t = threadIdx.x;
    int lane = t & 63;
    int w = t >> 6;
    const int chunk = (N_NODES + 1023) / 1024;  // 49
    int start = t * chunk;
    int end = start + chunk; if (end > N_NODES) end = N_NODES;
    int s = 0;
    for (int i = start; i < end; ++i) s += deg[i];
    // inclusive wave scan
    int v = s;
    #pragma unroll
    for (int off = 1; off < 64; off <<= 1) {
        int o = __shfl_up(v, off);
        if (lane >= off) v += o;
    }
    if (lane == 63) wsum[w] = v;
    __syncthreads();
    if (w == 0 && lane < 16) {
        int x = wsum[lane];
        #pragma unroll
        for (int off = 1; off < 16; off <<= 1) {
            int o = __shfl_up(x, off);
            if (lane >= off) x += o;
        }
        wsum[lane] = x;   // inclusive across waves
    }
    __syncthreads();
    int base = (w > 0 ? wsum[w - 1] : 0) + (v - s);  // exclusive prefix
    int a = base;
    for (int i = start; i < end; ++i) {
        rowptr[i] = a; cursor[i] = a; a += deg[i];
    }
    if (t == 0) rowptr[N_NODES] = wsum[15];
}

__global__ void scatter_kernel(const int* __restrict__ ei,
                               int* __restrict__ cursor, int* __restrict__ csr) {
    int e = blockIdx.x * 256 + threadIdx.x;
    if (e < N_EDGES) {
        int d = ei[N_EDGES + e];
        int s = ei[e];
        int p = atomicAdd(&cursor[d], 1);
        csr[p] = s;
    }
}

// Deterministic adjacency: ascending sort of each node's neighbor list.
// Wave-per-node 64-lane bitonic sort; degree > 64 falls back to insertion.
__global__ __launch_bounds__(256) void sort_adj_kernel(
        const int* __restrict__ rowptr, int* __restrict__ csr) {
    int lane = threadIdx.x & 63;
    int node = blockIdx.x * 4 + (threadIdx.x >> 6);
    if (node >= N_NODES) return;
    int beg = rowptr[node];
    int end = rowptr[node + 1];
    int d = end - beg;
    if (d <= 1) return;
    if (d <= 64) {
        int v = (lane < d) ? csr[beg + lane] : 0x7fffffff;
        #pragma unroll
        for (int k = 2; k <= 64; k <<= 1) {
            #pragma unroll
            for (int j = k >> 1; j > 0; j >>= 1) {
                int other = __shfl_xor(v, j);
                bool up    = ((lane & k) == 0);
                bool lower = ((lane & j) == 0);
                int mn = (v < other) ? v : other;
                int mx = (v < other) ? other : v;
                v = (up == lower) ? mn : mx;
            }
        }
        if (lane < d) csr[beg + lane] = v;
    } else if (lane == 0) {
        for (int i = beg + 1; i < end; ++i) {
            int vv = csr[i];
            int j = i - 1;
            while (j >= beg && csr[j] > vv) { csr[j + 1] = csr[j]; --j; }
            csr[j + 1] = vv;
        }
    }
}

// ---------------------------------------------------------------------------
// Layer-0 GIN aggregate: hpre[i] = x[i] + sum_{j->i} x[j]  (raw x, csr order)
// ---------------------------------------------------------------------------
__global__ __launch_bounds__(256) void agg_kernel(
        const float* __restrict__ x, const int* __restrict__ rowptr,
        const int* __restrict__ csr, float* __restrict__ hpre) {
    int lane = threadIdx.x & 63;
    int node = __builtin_amdgcn_readfirstlane(blockIdx.x * 4 + (threadIdx.x >> 6));
    if (node >= N_NODES) return;
    int beg = rowptr[node];
    int end = rowptr[node + 1];
    const float2* xp = (const float2*)x;
    float2 acc = xp[(size_t)node * 64 + lane];
    int e = beg;
    for (; e + 3 < end; e += 4) {
        int s0 = csr[e];
        int s1 = csr[e + 1];
        int s2 = csr[e + 2];
        int s3 = csr[e + 3];
        float2 v0 = xp[(size_t)s0 * 64 + lane];
        float2 v1 = xp[(size_t)s1 * 64 + lane];
        float2 v2 = xp[(size_t)s2 * 64 + lane];
        float2 v3 = xp[(size_t)s3 * 64 + lane];
        acc.x += v0.x; acc.y += v0.y;   // keep exact sequential order
        acc.x += v1.x; acc.y += v1.y;
        acc.x += v2.x; acc.y += v2.y;
        acc.x += v3.x; acc.y += v3.y;
    }
    for (; e < end; ++e) {
        int s0 = csr[e];
        float2 v0 = xp[(size_t)s0 * 64 + lane];
        acc.x += v0.x; acc.y += v0.y;
    }
    ((float2*)hpre)[(size_t)node * 64 + lane] = acc;
}

// ---------------------------------------------------------------------------
// Fused finalize(layer l-1) + aggregate(layer l).
// ---------------------------------------------------------------------------
#define XFORM(hin, x0, x1)                                              \
    {                                                                   \
        float t0_ = (hin.x - mu2.x) * iv2.x * g2.x + be2.x;             \
        float t1_ = (hin.y - mu2.y) * iv2.y * g2.y + be2.y;             \
        x0 = (t0_ > 0.f) ? t0_ : NEG_SLOPE * t0_;                       \
        x1 = (t1_ > 0.f) ? t1_ : NEG_SLOPE * t1_;                       \
    }

__global__ __launch_bounds__(256) void gather_fin_kernel(
        const float* __restrict__ hprev,
        const float* __restrict__ mu_v, const float* __restrict__ inv_v,
        const float* __restrict__ gamma, const float* __restrict__ beta,
        const float* __restrict__ gumbel_l, const int* __restrict__ batch,
        const int* __restrict__ rowptr, const int* __restrict__ csr,
        float* __restrict__ nc_out, float* __restrict__ gc_out,
        float* __restrict__ hpre) {
    int lane = threadIdx.x & 63;
    int node = __builtin_amdgcn_readfirstlane(blockIdx.x * 4 + (threadIdx.x >> 6));
    if (node >= N_NODES) return;

    float2 mu2 = ((const float2*)mu_v)[lane];
    float2 iv2 = ((const float2*)inv_v)[lane];
    float2 g2  = ((const float2*)gamma)[lane];
    float2 be2 = ((const float2*)beta)[lane];

    const float2* hp = (const float2*)hprev;
    float2 hv = hp[(size_t)node * 64 + lane];
    float hb0 = (hv.x - mu2.x) * iv2.x * g2.x + be2.x;
    float hb1 = (hv.y - mu2.y) * iv2.y * g2.y + be2.y;

    // ---- finalize part (layer l-1): argmax(hb + gumbel), nc, gc ----
    {
        float2 gm = ((const float2*)gumbel_l)[(size_t)node * 64 + lane];
        float y0 = hb0 + gm.x;   // TAU == 1.0
        float y1 = hb1 + gm.y;
        float bv; int bi;
        if (y1 > y0) { bv = y1; bi = 2 * lane + 1; }
        else         { bv = y0; bi = 2 * lane; }
        #pragma unroll
        for (int off = 32; off > 0; off >>= 1) {
            float ov = __shfl_xor(bv, off);
            int   oi = __shfl_xor(bi, off);
            if (ov > bv || (ov == bv && oi < bi)) { bv = ov; bi = oi; }
        }
        float2 nc;
        nc.x = (bi == 2 * lane)     ? 1.0f : 0.0f;
        nc.y = (bi == 2 * lane + 1) ? 1.0f : 0.0f;
        ((float2*)nc_out)[(size_t)node * 64 + lane] = nc;
        if (lane == 0) atomicExch(&gc_out[(size_t)batch[node] * EMB + bi], 1.0f);
    }

    // ---- aggregate part (layer l): acc = x[node] + sum x[nbr], csr order ----
    float2 acc;
    acc.x = (hb0 > 0.f) ? hb0 : NEG_SLOPE * hb0;
    acc.y = (hb1 > 0.f) ? hb1 : NEG_SLOPE * hb1;

    int beg = rowptr[node];
    int end = rowptr[node + 1];
    int e = beg;
    for (; e + 3 < end; e += 4) {
        int s0 = csr[e];
        int s1 = csr[e + 1];
        int s2 = csr[e + 2];
        int s3 = csr[e + 3];
        float2 h0 = hp[(size_t)s0 * 64 + lane];
        float2 h1 = hp[(size_t)s1 * 64 + lane];
        float2 h2 = hp[(size_t)s2 * 64 + lane];
        float2 h3 = hp[(size_t)s3 * 64 + lane];
        float a0, b0v, a1, b1v, a2, b2v, a3, b3v;
        XFORM(h0, a0, b0v)
        XFORM(h1, a1, b1v)
        XFORM(h2, a2, b2v)
        XFORM(h3, a3, b3v)
        acc.x += a0; acc.y += b0v;   // keep exact sequential order
        acc.x += a1; acc.y += b1v;
        acc.x += a2; acc.y += b2v;
        acc.x += a3; acc.y += b3v;
    }
    for (; e < end; ++e) {
        int s0 = csr[e];
        float2 h0 = hp[(size_t)s0 * 64 + lane];
        float a0, b0v;
        XFORM(h0, a0, b0v)
        acc.x += a0; acc.y += b0v;
    }
    ((float2*)hpre)[(size_t)node * 64 + lane] = acc;
}

// ---------------------------------------------------------------------------
// Fused MLP, wave-column structure, 512 threads (8 waves), BM = 128:
//   lane handles rows {lane, lane+64}; wave owns 16 columns wid*16..+15.
// Per k a wave needs only 16 wave-uniform W dwords (one s_load_dwordx16):
// half the SGPR pressure per prefetched k vs the 32-col version, and
// occupancy doubles to 4 waves/SIMD at unchanged LDS (67.6 KB, 2 blk/CU).
// Per-output accumulation is strict k=0..127 ascending (bitwise-identical;
// only the thread<->column ownership map changed).
// ---------------------------------------------------------------------------
__global__ __launch_bounds__(512) void mlp_kernel(
        float* __restrict__ HB,
        const float* __restrict__ W1, const float* __restrict__ b1,
        const float* __restrict__ W2, const float* __restrict__ b2,
        float* __restrict__ pstat) {
    __shared__ float As[BM][EMB + 4];   // 128 x 132 = 67.6 KB

    const int t    = threadIdx.x;
    const int lane = t & 63;
    const int wid  = __builtin_amdgcn_readfirstlane(t >> 6);   // 0..7
    const int wcol = wid * 16;
    const int row0 = blockIdx.x * BM;

    // ---- stage A tile (row-major, zero-padded tail rows) ----
    {
        const float4* Ag = (const float4*)HB;
        #pragma unroll
        for (int rep = 0; rep < 8; ++rep) {
            int v  = t + rep * 512;
            int r  = v >> 5;
            int c4 = v & 31;
            int gr = row0 + r;
            float4 val = (gr < N_NODES) ? Ag[(size_t)gr * 32 + c4]
                                        : make_float4(0.f, 0.f, 0.f, 0.f);
            *(float4*)&As[r][c4 * 4] = val;
        }
    }
    __syncthreads();

    float acc0[16], acc1[16];
    #pragma unroll
    for (int j = 0; j < 16; ++j) { acc0[j] = 0.f; acc1[j] = 0.f; }

    // ---- phase 1: acc = A(rows) @ W1(:, wcol..wcol+15), k ascending ----
    {
        const float* Wb = W1 + wcol;
        #pragma unroll 2
        for (int k4 = 0; k4 < 32; ++k4) {
            float4 a4 = *(const float4*)&As[lane][k4 * 4];
            float4 c4 = *(const float4*)&As[lane + 64][k4 * 4];
            const float* wk = Wb + (size_t)(k4 * 4) * EMB;
            #pragma unroll
            for (int dk = 0; dk < 4; ++dk) {
                float a = (dk == 0) ? a4.x : (dk == 1) ? a4.y
                         : (dk == 2) ? a4.z : a4.w;
                float c = (dk == 0) ? c4.x : (dk == 1) ? c4.y
                         : (dk == 2) ? c4.z : c4.w;
                const float* w = wk + (size_t)dk * EMB;
                #pragma unroll
                for (int j = 0; j < 16; ++j) {
                    acc0[j] += a * w[j];
                    acc1[j] += c * w[j];
                }
            }
        }
    }

    __syncthreads();   // all phase-1 reads of As done before T overwrites it

    // ---- transform: T = leaky(acc + b1), write back to As rows ----
    #pragma unroll
    for (int q = 0; q < 4; ++q) {
        float4 o0, o1;
        #pragma unroll
        for (int i = 0; i < 4; ++i) {
            float bias = b1[wcol + q * 4 + i];
            float v0 = acc0[q * 4 + i] + bias;
            float v1 = acc1[q * 4 + i] + bias;
            v0 = (v0 > 0.f) ? v0 : NEG_SLOPE * v0;
            v1 = (v1 > 0.f) ? v1 : NEG_SLOPE * v1;
            (&o0.x)[i] = v0;
            (&o1.x)[i] = v1;
            acc0[q * 4 + i] = 0.f;
            acc1[q * 4 + i] = 0.f;
        }
        *(float4*)&As[lane][wcol + q * 4]      = o0;
        *(float4*)&As[lane + 64][wcol + q * 4] = o1;
    }
    __syncthreads();   // T visible to all waves

    // ---- phase 2: acc = T(rows) @ W2(:, wcol..wcol+15), k ascending ----
    {
        const float* Wb = W2 + wcol;
        #pragma unroll 2
        for (int k4 = 0; k4 < 32; ++k4) {
            float4 a4 = *(const float4*)&As[lane][k4 * 4];
            float4 c4 = *(const float4*)&As[lane + 64][k4 * 4];
            const float* wk = Wb + (size_t)(k4 * 4) * EMB;
            #pragma unroll
            for (int dk = 0; dk < 4; ++dk) {
                float a = (dk == 0) ? a4.x : (dk == 1) ? a4.y
                         : (dk == 2) ? a4.z : a4.w;
                float c = (dk == 0) ? c4.x : (dk == 1) ? c4.y
                         : (dk == 2) ? c4.z : c4.w;
                const float* w = wk + (size_t)dk * EMB;
                #pragma unroll
                for (int j = 0; j < 16; ++j) {
                    acc0[j] += a * w[j];
                    acc1[j] += c * w[j];
                }
            }
        }
    }

    // ---- epilogue: h = acc + b2 (in place), store to global ----
    #pragma unroll
    for (int j = 0; j < 16; ++j) {
        float bias = b2[wcol + j];
        acc0[j] += bias;
        acc1[j] += bias;
    }
    const int gr0 = row0 + lane;
    const int gr1 = row0 + 64 + lane;
    if (gr0 < N_NODES) {
        #pragma unroll
        for (int q = 0; q < 4; ++q)
            *(float4*)&HB[(size_t)gr0 * EMB + wcol + q * 4] =
                make_float4(acc0[q * 4 + 0], acc0[q * 4 + 1],
                            acc0[q * 4 + 2], acc0[q * 4 + 3]);
    }
    if (gr1 < N_NODES) {
        #pragma unroll
        for (int q = 0; q < 4; ++q)
            *(float4*)&HB[(size_t)gr1 * EMB + wcol + q * 4] =
                make_float4(acc1[q * 4 + 0], acc1[q * 4 + 1],
                            acc1[q * 4 + 2], acc1[q * 4 + 3]);
    }

    // ---- stash h in LDS, per-block BN partials (ascending-row order) ----
    __syncthreads();   // all phase-2 reads of As done before h overwrites it
    #pragma unroll
    for (int q = 0; q < 4; ++q) {
        *(float4*)&As[lane][wcol + q * 4] =
            make_float4(acc0[q * 4 + 0], acc0[q * 4 + 1],
                        acc0[q * 4 + 2], acc0[q * 4 + 3]);
        *(float4*)&As[lane + 64][wcol + q * 4] =
            make_float4(acc1[q * 4 + 0], acc1[q * 4 + 1],
                        acc1[q * 4 + 2], acc1[q * 4 + 3]);
    }
    __syncthreads();

    if (t < EMB) {
        int valid = N_NODES - row0; if (valid > BM) valid = BM;
        float s = 0.f, q = 0.f;
        for (int r = 0; r < valid; ++r) {
            float v = As[r][t];
            s += v;
            q += v * v;
        }
        float2 o; o.x = s; o.y = q;
        *(float2*)&pstat[(size_t)blockIdx.x * 256 + 2 * t] = o;
    }
}

// ---------------------------------------------------------------------------
// Per-block partials -> mu / inv. 1024 threads: 8 b-chunks x 128 columns,
// strict ascending order within chunks and ascending-chunk combine.
// ---------------------------------------------------------------------------
__global__ __launch_bounds__(1024) void bn_stats_kernel(
        const float* __restrict__ pstat,
        float* __restrict__ mu_out, float* __restrict__ inv_out) {
    __shared__ float2 part[8][128];
    int t   = threadIdx.x;
    int col = t & 127;
    int ch  = t >> 7;
    const int CH = (NBLK + 7) / 8;   // 49
    int b  = ch * CH;
    int be = b + CH; if (be > NBLK) be = NBLK;
    const float2* p = (const float2*)pstat;  // [b][128] float2
    float s = 0.f, q = 0.f;
    for (; b + 4 <= be; b += 4) {
        float2 v0 = p[(size_t)(b + 0) * 128 + col];
        float2 v1 = p[(size_t)(b + 1) * 128 + col];
        float2 v2 = p[(size_t)(b + 2) * 128 + col];
        float2 v3 = p[(size_t)(b + 3) * 128 + col];
        s += v0.x; q += v0.y;
        s += v1.x; q += v1.y;
        s += v2.x; q += v2.y;
        s += v3.x; q += v3.y;
    }
    for (; b < be; ++b) {
        float2 v = p[(size_t)b * 128 + col];
        s += v.x; q += v.y;
    }
    float2 o; o.x = s; o.y = q;
    part[ch][col] = o;
    __syncthreads();
    if (t < 128) {
        float S = 0.f, Q = 0.f;
        #pragma unroll
        for (int c = 0; c < 8; ++c) {   // ascending chunk order
            float2 v = part[c][t];
            S += v.x; Q += v.y;
        }
        const float invN = 1.f / (float)N_NODES;
        float mu  = S * invN;
        float var = Q * invN - mu * mu;
        mu_out[t]  = mu;
        inv_out[t] = rsqrtf(var + BN_EPS);
    }
}

// ---------------------------------------------------------------------------
// Tail finalize for the last layer (no aggregation, no xnext)
// ---------------------------------------------------------------------------
__global__ __launch_bounds__(256) void finalize_tail_kernel(
        const float* __restrict__ h,
        const float* __restrict__ mu_v, const float* __restrict__ inv_v,
        const float* __restrict__ gamma, const float* __restrict__ beta,
        const float* __restrict__ gumbel_l, const int* __restrict__ batch,
        float* __restrict__ nc_out, float* __restrict__ gc_out) {
    int lane = threadIdx.x & 63;
    int node = blockIdx.x * 4 + (threadIdx.x >> 6);

    float2 hv  = ((const float2*)h)[(size_t)node * 64 + lane];
    float2 mu2 = ((const float2*)mu_v)[lane];
    float2 iv2 = ((const float2*)inv_v)[lane];
    float2 g2  = ((const float2*)gamma)[lane];
    float2 be2 = ((const float2*)beta)[lane];
    float2 gm  = ((const float2*)gumbel_l)[(size_t)node * 64 + lane];

    float hb0 = (hv.x - mu2.x) * iv2.x * g2.x + be2.x;
    float hb1 = (hv.y - mu2.y) * iv2.y * g2.y + be2.y;
    float y0 = hb0 + gm.x;   // TAU == 1.0
    float y1 = hb1 + gm.y;

    float bv; int bi;
    if (y1 > y0) { bv = y1; bi = 2 * lane + 1; }
    else         { bv = y0; bi = 2 * lane; }
    #pragma unroll
    for (int off = 32; off > 0; off >>= 1) {
        float ov = __shfl_xor(bv, off);
        int   oi = __shfl_xor(bi, off);
        if (ov > bv || (ov == bv && oi < bi)) { bv = ov; bi = oi; }
    }

    float2 nc;
    nc.x = (bi == 2 * lane)     ? 1.0f : 0.0f;
    nc.y = (bi == 2 * lane + 1) ? 1.0f : 0.0f;
    ((float2*)nc_out)[(size_t)node * 64 + lane] = nc;

    if (lane == 0) atomicExch(&gc_out[(size_t)batch[node] * EMB + bi], 1.0f);
}

// ---------------------------------------------------------------------------
// logits = gc_last @ dense_W + dense_b
// ---------------------------------------------------------------------------
__global__ __launch_bounds__(128) void logits_kernel(
        const float* __restrict__ gc, const float* __restrict__ W,
        const float* __restrict__ b, float* __restrict__ out) {
    __shared__ float row[EMB];
    int g = blockIdx.x;
    int t = threadIdx.x;
    row[t] = gc[g * EMB + t];
    __syncthreads();
    if (t < N_CLASSES) {
        float acc = b[t];
        for (int k = 0; k < EMB; ++k) acc += row[k] * W[k * N_CLASSES + t];
        out[g * N_CLASSES + t] = acc;
    }
}

// ---------------------------------------------------------------------------
extern "C" void kernel_launch(void* const* d_in, const int* in_sizes, int n_in,
                              void* d_out, int out_size, void* d_ws, size_t ws_size,
                              hipStream_t stream) {
    const float* x_in    = (const float*)d_in[0];
    const int*   ei      = (const int*)  d_in[1];
    const int*   batch   = (const int*)  d_in[2];
    const float* W1      = (const float*)d_in[3];
    const float* b1      = (const float*)d_in[4];
    const float* W2      = (const float*)d_in[5];
    const float* b2      = (const float*)d_in[6];
    const float* gamma   = (const float*)d_in[7];
    const float* beta    = (const float*)d_in[8];
    const float* gumbel  = (const float*)d_in[9];
    const float* dW      = (const float*)d_in[10];
    const float* db      = (const float*)d_in[11];

    float* out = (float*)d_out;
    const size_t NC_OFF = (size_t)N_GRAPHS * N_CLASSES;
    const size_t GC_OFF = NC_OFF + (size_t)L_LAYERS * N_NODES * EMB;
    float* logits_out = out;
    float* nc_out     = out + NC_OFF;
    float* gc_out     = out + GC_OFF;

    // workspace layout
    float* bufA    = (float*)d_ws;                    // 6.4M floats
    float* bufB    = bufA + (size_t)N_NODES * EMB;    // 6.4M floats
    float* pstat   = bufB + (size_t)N_NODES * EMB;    // NBLK*256 (sum/sq interleaved)
    float* mu_v    = pstat + (size_t)NBLK * 256;      // 128
    float* inv_v   = mu_v + EMB;                      // 128
    int*   rowptr  = (int*)(inv_v + EMB);             // 50001
    int*   cursor  = rowptr + (N_NODES + 1);          // 50000
    int*   csr     = cursor + N_NODES;                // 800000
    int*   deg     = csr + N_EDGES;                   // 50000

    // CSR build (deterministic after per-node sort)
    hipMemsetAsync(deg, 0, N_NODES * sizeof(int), stream);
    deg_kernel<<<(N_EDGES + 255) / 256, 256, 0, stream>>>(ei, deg);
    scan_kernel<<<1, 1024, 0, stream>>>(deg, rowptr, cursor);
    scatter_kernel<<<(N_EDGES + 255) / 256, 256, 0, stream>>>(ei, cursor, csr);
    sort_adj_kernel<<<(N_NODES + 3) / 4, 256, 0, stream>>>(rowptr, csr);

    hipMemsetAsync(gc_out, 0,
                   (size_t)L_LAYERS * N_GRAPHS * EMB * sizeof(float), stream);

    float* buf[2] = { bufA, bufB };

    // layer 0: raw aggregate from x_in
    agg_kernel<<<(N_NODES + 3) / 4, 256, 0, stream>>>(x_in, rowptr, csr, bufA);
    mlp_kernel<<<NBLK, 512, 0, stream>>>(bufA, W1, b1, W2, b2, pstat);
    bn_stats_kernel<<<1, 1024, 0, stream>>>(pstat, mu_v, inv_v);

    for (int l = 1; l < L_LAYERS; ++l) {
        float* hprev = buf[(l - 1) & 1];
        float* hcur  = buf[l & 1];
        gather_fin_kernel<<<(N_NODES + 3) / 4, 256, 0, stream>>>(
            hprev, mu_v, inv_v,
            gamma + (size_t)(l - 1) * EMB, beta + (size_t)(l - 1) * EMB,
            gumbel + (size_t)(l - 1) * N_NODES * EMB, batch,
            rowptr, csr,
            nc_out + (size_t)(l - 1) * N_NODES * EMB,
            gc_out + (size_t)(l - 1) * N_GRAPHS * EMB,
            hcur);
        mlp_kernel<<<NBLK, 512, 0, stream>>>(
            hcur,
            W1 + (size_t)l * EMB * EMB, b1 + (size_t)l * EMB,
            W2 + (size_t)l * EMB * EMB, b2 + (size_t)l * EMB,
            pstat);
        bn_stats_kernel<<<1, 1024, 0, stream>>>(pstat, mu_v, inv_v);
    }

    // finalize last layer (no aggregation)
    finalize_tail_kernel<<<(N_NODES + 3) / 4, 256, 0, stream>>>(
        buf[(L_LAYERS - 1) & 1], mu_v, inv_v,
        gamma + (size_t)(L_LAYERS - 1) * EMB, beta + (size_t)(L_LAYERS - 1) * EMB,
        gumbel + (size_t)(L_LAYERS - 1) * N_NODES * EMB, batch,
        nc_out + (size_t)(L_LAYERS - 1) * N_NODES * EMB,
        gc_out + (size_t)(L_LAYERS - 1) * N_GRAPHS * EMB);

    logits_kernel<<<N_GRAPHS, 128, 0, stream>>>(
        gc_out + (size_t)(L_LAYERS - 1) * N_GRAPHS * EMB, dW, db, logits_out);
}